// Round 7
// baseline (160.180 us; speedup 1.0000x reference)
//
#include <hip/hip_runtime.h>

#define N_NODES 100000
#define N_EDGES 600000
#define D 128
#define K2 256          // stacked K = [agg | x]
#define SCAN_TILE 1024
#define NBLK 98   // ceil(N_NODES / SCAN_TILE)

typedef __attribute__((ext_vector_type(8))) short short8;
typedef __attribute__((ext_vector_type(4))) float f32x4;

__device__ __forceinline__ unsigned short f2bf(float f) {
    union { float f; unsigned u; } v; v.f = f;
    unsigned u = v.u;
    u += 0x7FFFu + ((u >> 16) & 1u);     // round-to-nearest-even
    return (unsigned short)(u >> 16);
}

__device__ __forceinline__ float bf_lo(unsigned u) {
    union { unsigned u; float f; } v; v.u = u << 16; return v.f;
}
__device__ __forceinline__ float bf_hi(unsigned u) {
    union { unsigned u; float f; } v; v.u = u & 0xFFFF0000u; return v.f;
}

// ---------------------------------------------------------------------------
// zero_counts: custom fill (rocclr fillBuffer used a tiny grid: 39us for
// 400KB).  25600 x uint4 stores across 100 blocks -> ~3us.
// ---------------------------------------------------------------------------
__global__ void zero_counts_kernel(uint4* __restrict__ counts4) {
    int t = blockIdx.x * blockDim.x + threadIdx.x;
    if (t < N_NODES / 4) counts4[t] = make_uint4(0, 0, 0, 0);
}

// ---------------------------------------------------------------------------
// Counting sort: hist -> 3-phase scan -> scatter_idx
// ---------------------------------------------------------------------------
__global__ void hist_kernel(const int* __restrict__ ei, int* __restrict__ counts) {
    int e = blockIdx.x * blockDim.x + threadIdx.x;
    if (e >= N_EDGES) return;
    atomicAdd(&counts[ei[N_EDGES + e]], 1);
}

__global__ __launch_bounds__(SCAN_TILE) void tile_sum_kernel(
        const int* __restrict__ counts, int* __restrict__ blockSums) {
    __shared__ int sh[SCAN_TILE];
    int t = threadIdx.x;
    int gid = blockIdx.x * SCAN_TILE + t;
    sh[t] = (gid < N_NODES) ? counts[gid] : 0;
    __syncthreads();
    for (int off = SCAN_TILE / 2; off > 0; off >>= 1) {
        if (t < off) sh[t] += sh[t + off];
        __syncthreads();
    }
    if (t == 0) blockSums[blockIdx.x] = sh[0];
}

__global__ void scan_blocks_kernel(const int* __restrict__ blockSums,
                                   int* __restrict__ blockOff) {
    __shared__ int sh[128];
    int t = threadIdx.x;
    int v = (t < NBLK) ? blockSums[t] : 0;
    sh[t] = v;
    __syncthreads();
    for (int off = 1; off < 128; off <<= 1) {
        int u = (t >= off) ? sh[t - off] : 0;
        __syncthreads();
        sh[t] += u;
        __syncthreads();
    }
    if (t < NBLK) blockOff[t] = sh[t] - v;
}

__global__ __launch_bounds__(SCAN_TILE) void scan_tile_kernel(
        const int* __restrict__ counts, const int* __restrict__ blockOff,
        int* __restrict__ offsets, int* __restrict__ cursor) {
    __shared__ int sh[SCAN_TILE];
    int t = threadIdx.x;
    int gid = blockIdx.x * SCAN_TILE + t;
    int v = (gid < N_NODES) ? counts[gid] : 0;
    sh[t] = v;
    __syncthreads();
    for (int off = 1; off < SCAN_TILE; off <<= 1) {
        int u = (t >= off) ? sh[t - off] : 0;
        __syncthreads();
        sh[t] += u;
        __syncthreads();
    }
    int excl = sh[t] - v + blockOff[blockIdx.x];
    if (gid < N_NODES) {
        offsets[gid] = excl;
        cursor[gid] = excl;
    }
    if (gid == N_NODES - 1) offsets[N_NODES] = excl + v;
}

__global__ void scatter_idx_kernel(const int* __restrict__ ei,
                                   int* __restrict__ cursor,
                                   int* __restrict__ srcSorted) {
    int e = blockIdx.x * blockDim.x + threadIdx.x;
    if (e >= N_EDGES) return;
    int s = ei[e];
    int t = ei[N_EDGES + e];
    int pos = atomicAdd(&cursor[t], 1);
    srcSorted[pos] = s;
}

// ---------------------------------------------------------------------------
// convert_x: x fp32 -> Amat[:,128:256) bf16.  MUST run before seg_sum.
// ---------------------------------------------------------------------------
__global__ void convert_x_kernel(const float* __restrict__ x,
                                 unsigned short* __restrict__ Amat) {
    int t = blockIdx.x * blockDim.x + threadIdx.x;
    if (t >= N_NODES * 16) return;
    int n = t >> 4, c8 = (t & 15) * 8;
    const float4* p = (const float4*)&x[(size_t)n * D + c8];
    float4 v0 = p[0], v1 = p[1];
    uint4 o;
    o.x = (unsigned)f2bf(v0.x) | ((unsigned)f2bf(v0.y) << 16);
    o.y = (unsigned)f2bf(v0.z) | ((unsigned)f2bf(v0.w) << 16);
    o.z = (unsigned)f2bf(v1.x) | ((unsigned)f2bf(v1.y) << 16);
    o.w = (unsigned)f2bf(v1.z) | ((unsigned)f2bf(v1.w) << 16);
    *(uint4*)&Amat[(size_t)n * K2 + 128 + c8] = o;
}

// ---------------------------------------------------------------------------
// seg_sum v2: one wave per node; TWO edges in flight per iteration.
// Lanes 0-31 handle edge p (cols (lane&31)*4, 8B load), lanes 32-63 edge p+1.
// fp32 partial acc per half; halves combined with shfl_xor(32) at the end.
// Reads cols [128,256) of other rows, writes cols [0,128) of own row.
// ---------------------------------------------------------------------------
__global__ void seg_sum_kernel(const int* __restrict__ offsets,
                               const int* __restrict__ srcSorted,
                               unsigned short* __restrict__ Amat) {
    int wid = (blockIdx.x * blockDim.x + threadIdx.x) >> 6;
    if (wid >= N_NODES) return;
    int lane = threadIdx.x & 63;
    int half = lane >> 5;
    int cq = (lane & 31) * 4;           // 4 bf16 cols = 8 B per lane
    int beg = offsets[wid], end = offsets[wid + 1];
    float4 acc = make_float4(0.f, 0.f, 0.f, 0.f);
    int p = beg + half;
    for (; p + 2 < end; p += 4) {       // 2 gathers in flight per half
        int s0 = srcSorted[p], s1 = srcSorted[p + 2];
        uint2 u0 = *(const uint2*)&Amat[(size_t)s0 * K2 + 128 + cq];
        uint2 u1 = *(const uint2*)&Amat[(size_t)s1 * K2 + 128 + cq];
        acc.x += bf_lo(u0.x) + bf_lo(u1.x);
        acc.y += bf_hi(u0.x) + bf_hi(u1.x);
        acc.z += bf_lo(u0.y) + bf_lo(u1.y);
        acc.w += bf_hi(u0.y) + bf_hi(u1.y);
    }
    if (p < end) {
        int s0 = srcSorted[p];
        uint2 u0 = *(const uint2*)&Amat[(size_t)s0 * K2 + 128 + cq];
        acc.x += bf_lo(u0.x);
        acc.y += bf_hi(u0.x);
        acc.z += bf_lo(u0.y);
        acc.w += bf_hi(u0.y);
    }
    acc.x += __shfl_xor(acc.x, 32);
    acc.y += __shfl_xor(acc.y, 32);
    acc.z += __shfl_xor(acc.z, 32);
    acc.w += __shfl_xor(acc.w, 32);
    if (half == 0) {
        uint2 o;
        o.x = (unsigned)f2bf(acc.x) | ((unsigned)f2bf(acc.y) << 16);
        o.y = (unsigned)f2bf(acc.z) | ((unsigned)f2bf(acc.w) << 16);
        *(uint2*)&Amat[(size_t)wid * K2 + cq] = o;
    }
}

// ---------------------------------------------------------------------------
// wprep: pack stacked weights [Wrel;Wroot] into MFMA B-fragment order, bf16.
// ---------------------------------------------------------------------------
__global__ void wprep_kernel(const float* __restrict__ Wrel,
                             const float* __restrict__ Wroot,
                             unsigned short* __restrict__ Wfrag) {
    int slot = blockIdx.x * blockDim.x + threadIdx.x;
    if (slot >= 4096) return;
    int lane = slot & 63;
    int ks = (slot >> 6) & 7;
    int ct = slot >> 9;
    int m = ct * 16 + (lane & 15);
    int k = ks * 32 + (lane >> 4) * 8;
    const float* src = (k < 128) ? &Wrel[(size_t)m * 128 + k]
                                 : &Wroot[(size_t)m * 128 + (k - 128)];
    uint4 o;
    o.x = (unsigned)f2bf(src[0]) | ((unsigned)f2bf(src[1]) << 16);
    o.y = (unsigned)f2bf(src[2]) | ((unsigned)f2bf(src[3]) << 16);
    o.z = (unsigned)f2bf(src[4]) | ((unsigned)f2bf(src[5]) << 16);
    o.w = (unsigned)f2bf(src[6]) | ((unsigned)f2bf(src[7]) << 16);
    *(uint4*)&Wfrag[(size_t)slot * 8] = o;
}

// ---------------------------------------------------------------------------
// gemm_mfma v2: out[n][m] = Amat[n][:] (bf16, K=256) . W + brel[m], fp32 out.
// One 128-row chunk per block; all 8 K-steps of A preloaded (MLP); epilogue
// via swizzled LDS transpose (reuses W space) + coalesced float4 stores.
// ---------------------------------------------------------------------------
__global__ __launch_bounds__(256, 2) void gemm_mfma(
        const unsigned short* __restrict__ Amat,
        const unsigned short* __restrict__ Wfrag,
        const float* __restrict__ brel,
        float* __restrict__ out) {
    __shared__ __align__(16) char smem[65536];
    short8* Wlds = (short8*)smem;
    float*  So   = (float*)smem;

    int tid = threadIdx.x;
    for (int i = tid; i < 4096; i += 256)
        Wlds[i] = *(const short8*)&Wfrag[(size_t)i * 8];
    __syncthreads();

    int lane = tid & 63;
    int w = tid >> 6;
    int n16 = lane & 15, kg = lane >> 4;
    long rowB = (long)blockIdx.x * 128;
    long row0 = rowB + w * 32;

    long r0 = row0 + n16;
    long r1 = row0 + 16 + n16;
    long cr0 = (r0 < N_NODES) ? r0 : (N_NODES - 1);
    long cr1 = (r1 < N_NODES) ? r1 : (N_NODES - 1);
    const short8* a0p = (const short8*)(Amat + cr0 * K2 + kg * 8);
    const short8* a1p = (const short8*)(Amat + cr1 * K2 + kg * 8);

    short8 a0v[8], a1v[8];
#pragma unroll
    for (int ks = 0; ks < 8; ++ks) {
        a0v[ks] = a0p[ks * 4];
        a1v[ks] = a1p[ks * 4];
    }

    f32x4 acc[2][8];
#pragma unroll
    for (int h = 0; h < 2; ++h)
#pragma unroll
        for (int ct = 0; ct < 8; ++ct)
            acc[h][ct] = (f32x4){0.f, 0.f, 0.f, 0.f};

#pragma unroll
    for (int ks = 0; ks < 8; ++ks) {
#pragma unroll
        for (int ct = 0; ct < 8; ++ct) {
            short8 b = Wlds[(ct * 8 + ks) * 64 + lane];
            acc[0][ct] = __builtin_amdgcn_mfma_f32_16x16x32_bf16(a0v[ks], b, acc[0][ct], 0, 0, 0);
            acc[1][ct] = __builtin_amdgcn_mfma_f32_16x16x32_bf16(a1v[ks], b, acc[1][ct], 0, 0, 0);
        }
    }

    __syncthreads();   // all waves done reading Wlds
    // D layout (m89): col = lane&15, row = 4*(lane>>4) + reg.
#pragma unroll
    for (int h = 0; h < 2; ++h)
#pragma unroll
        for (int ct = 0; ct < 8; ++ct) {
            float bias = brel[ct * 16 + n16];
#pragma unroll
            for (int r = 0; r < 4; ++r) {
                int lrow = w * 32 + h * 16 + kg * 4 + r;
                int col = ct * 16 + n16;
                So[lrow * 128 + (col ^ ((lrow & 7) << 2))] = acc[h][ct][r] + bias;
            }
        }
    __syncthreads();

#pragma unroll
    for (int j = 0; j < 16; ++j) {
        int g = tid + j * 256;
        int lrow = g >> 5;
        int q = g & 31;
        long grow = rowB + lrow;
        if (grow < N_NODES) {
            float4 v = *(float4*)&So[lrow * 128 + ((q * 4) ^ ((lrow & 7) << 2))];
            *(float4*)&out[grow * 128 + q * 4] = v;
        }
    }
}

// ---------------------------------------------------------------------------
// Fallback (ws too small): atomic scatter + fp32 GEMM (round-1 path).
// ---------------------------------------------------------------------------
__global__ void scatter_kernel(const float* __restrict__ x,
                               const int* __restrict__ ei,
                               float* __restrict__ agg) {
    int gid = blockIdx.x * blockDim.x + threadIdx.x;
    int e = gid >> 5;
    if (e >= N_EDGES) return;
    int q = (gid & 31) * 4;
    int s = ei[e];
    int t = ei[N_EDGES + e];
    float4 v = *(const float4*)&x[(size_t)s * D + q];
    float* ap = &agg[(size_t)t * D + q];
    atomicAdd(ap + 0, v.x);
    atomicAdd(ap + 1, v.y);
    atomicAdd(ap + 2, v.z);
    atomicAdd(ap + 3, v.w);
}

__global__ __launch_bounds__(256, 1) void fused_gemm(
        const float* __restrict__ agg, const float* __restrict__ x,
        const float* __restrict__ Wrel, const float* __restrict__ brel,
        const float* __restrict__ Wroot, float* __restrict__ out,
        int nChunks) {
    __shared__ float W2t[256][128];
    __shared__ float rows[16][256];
    int tid = threadIdx.x;
    for (int idx = tid; idx < 256 * 128; idx += 256) {
        int k = idx >> 7, m = idx & 127;
        W2t[k][m] = (k < 128) ? Wrel[m * 128 + k] : Wroot[m * 128 + (k - 128)];
    }
    __syncthreads();
    int mq = tid & 31, rg = tid >> 5, m4 = mq * 4;
    for (int chunk = blockIdx.x; chunk < nChunks; chunk += gridDim.x) {
        size_t row0 = (size_t)chunk * 16;
        __syncthreads();
        for (int j = 0; j < 4; ++j) {
            int i = (tid + j * 256) * 4;
            int r = i >> 8, c = i & 255;
            float4 v;
            if (c < 128) v = *(const float4*)&agg[(row0 + r) * D + c];
            else         v = *(const float4*)&x[(row0 + r) * D + (c - 128)];
            *(float4*)&rows[r][c] = v;
        }
        __syncthreads();
        float4 acc0 = make_float4(0, 0, 0, 0), acc1 = make_float4(0, 0, 0, 0);
#pragma unroll 8
        for (int k = 0; k < 256; ++k) {
            float4 wv = *(const float4*)&W2t[k][m4];
            float A0 = rows[rg][k], A1 = rows[rg + 8][k];
            acc0.x = fmaf(A0, wv.x, acc0.x); acc0.y = fmaf(A0, wv.y, acc0.y);
            acc0.z = fmaf(A0, wv.z, acc0.z); acc0.w = fmaf(A0, wv.w, acc0.w);
            acc1.x = fmaf(A1, wv.x, acc1.x); acc1.y = fmaf(A1, wv.y, acc1.y);
            acc1.z = fmaf(A1, wv.z, acc1.z); acc1.w = fmaf(A1, wv.w, acc1.w);
        }
        float4 b = *(const float4*)&brel[m4];
        *(float4*)&out[(row0 + rg) * D + m4] =
            make_float4(acc0.x + b.x, acc0.y + b.y, acc0.z + b.z, acc0.w + b.w);
        *(float4*)&out[(row0 + rg + 8) * D + m4] =
            make_float4(acc1.x + b.x, acc1.y + b.y, acc1.z + b.z, acc1.w + b.w);
    }
}

extern "C" void kernel_launch(void* const* d_in, const int* in_sizes, int n_in,
                              void* d_out, int out_size, void* d_ws, size_t ws_size,
                              hipStream_t stream) {
    const float* x     = (const float*)d_in[0];
    const int*   ei    = (const int*)d_in[1];
    const float* Wrel  = (const float*)d_in[2];
    const float* brel  = (const float*)d_in[3];
    const float* Wroot = (const float*)d_in[4];
    float* out = (float*)d_out;

    const size_t amatBytes = (size_t)N_NODES * K2 * sizeof(unsigned short); // 51.2 MB
    const size_t offBytes  = (size_t)(N_NODES + 1) * sizeof(int);
    const size_t curBytes  = (size_t)N_NODES * sizeof(int);
    const size_t srcBytes  = (size_t)N_EDGES * sizeof(int);
    const size_t cntBytes  = (size_t)N_NODES * sizeof(int);
    const size_t blkBytes  = (size_t)NBLK * sizeof(int);
    const size_t wfBytes   = (size_t)4096 * 8 * sizeof(unsigned short);     // 64 KB
    auto align16 = [](size_t v) { return (v + 15) & ~(size_t)15; };

    size_t o_amat = 0;
    size_t o_off  = align16(o_amat + amatBytes);
    size_t o_cur  = align16(o_off + offBytes);
    size_t o_src  = align16(o_cur + curBytes);
    size_t o_cnt  = align16(o_src + srcBytes);
    size_t o_bs   = align16(o_cnt + cntBytes);
    size_t o_bo   = align16(o_bs + blkBytes);
    size_t o_wf   = align16(o_bo + blkBytes);
    size_t total  = o_wf + wfBytes;

    if (ws_size >= total) {
        char* ws = (char*)d_ws;
        unsigned short* Amat  = (unsigned short*)(ws + o_amat);
        int*   offsets   = (int*)(ws + o_off);
        int*   cursor    = (int*)(ws + o_cur);
        int*   srcSorted = (int*)(ws + o_src);
        int*   counts    = (int*)(ws + o_cnt);
        int*   blockSums = (int*)(ws + o_bs);
        int*   blockOff  = (int*)(ws + o_bo);
        unsigned short* Wfrag = (unsigned short*)(ws + o_wf);

        zero_counts_kernel<<<(N_NODES / 4 + 255) / 256, 256, 0, stream>>>((uint4*)counts);
        hist_kernel<<<(N_EDGES + 255) / 256, 256, 0, stream>>>(ei, counts);
        wprep_kernel<<<16, 256, 0, stream>>>(Wrel, Wroot, Wfrag);
        convert_x_kernel<<<(N_NODES * 16 + 255) / 256, 256, 0, stream>>>(x, Amat);
        tile_sum_kernel<<<NBLK, SCAN_TILE, 0, stream>>>(counts, blockSums);
        scan_blocks_kernel<<<1, 128, 0, stream>>>(blockSums, blockOff);
        scan_tile_kernel<<<NBLK, SCAN_TILE, 0, stream>>>(counts, blockOff, offsets, cursor);
        scatter_idx_kernel<<<(N_EDGES + 255) / 256, 256, 0, stream>>>(ei, cursor, srcSorted);
        seg_sum_kernel<<<(N_NODES * 64 + 255) / 256, 256, 0, stream>>>(offsets, srcSorted, Amat);
        gemm_mfma<<<(N_NODES + 127) / 128, 256, 0, stream>>>(Amat, Wfrag, brel, out);
    } else {
        // Fallback: atomic scatter + fp32 GEMM.
        float* agg = (ws_size >= (size_t)N_NODES * D * sizeof(float)) ? (float*)d_ws : out;
        hipMemsetAsync(agg, 0, (size_t)N_NODES * D * sizeof(float), stream);
        scatter_kernel<<<(N_EDGES * 32 + 255) / 256, 256, 0, stream>>>(x, ei, agg);
        fused_gemm<<<256, 256, 0, stream>>>(agg, x, Wrel, brel, Wroot, out,
                                            N_NODES / 16);
    }
}

// Round 8
// 141.210 us; speedup vs baseline: 1.1343x; 1.1343x over previous
//
#include <hip/hip_runtime.h>

#define N_NODES 100000
#define N_EDGES 600000
#define D 128
#define K2 256          // stacked K = [agg | x]
#define SCAN_TILE 1024
#define NBLK 98         // ceil(N_NODES / SCAN_TILE)

#define CONV_BLOCKS 6250   // N_NODES*16 / 256
#define ZERO_BLOCKS 98     // ceil(25000 uint4 / 256)
#define WPREP_BLOCKS 16    // 4096 slots / 256

typedef __attribute__((ext_vector_type(8))) short short8;
typedef __attribute__((ext_vector_type(4))) float f32x4;

__device__ __forceinline__ unsigned short f2bf(float f) {
    union { float f; unsigned u; } v; v.f = f;
    unsigned u = v.u;
    u += 0x7FFFu + ((u >> 16) & 1u);     // round-to-nearest-even
    return (unsigned short)(u >> 16);
}

__device__ __forceinline__ float bf_lo(unsigned u) {
    union { unsigned u; float f; } v; v.u = u << 16; return v.f;
}
__device__ __forceinline__ float bf_hi(unsigned u) {
    union { unsigned u; float f; } v; v.u = u & 0xFFFF0000u; return v.f;
}

// ---------------------------------------------------------------------------
// prep: fused {convert_x | zero_counts | wprep} (independent tasks, one
// launch instead of three).  Block-range dispatch.
// ---------------------------------------------------------------------------
__global__ void prep_kernel(const float* __restrict__ x,
                            unsigned short* __restrict__ Amat,
                            uint4* __restrict__ counts4,
                            const float* __restrict__ Wrel,
                            const float* __restrict__ Wroot,
                            unsigned short* __restrict__ Wfrag) {
    int b = blockIdx.x;
    int tid = threadIdx.x;
    if (b < CONV_BLOCKS) {
        // convert_x: x fp32 -> Amat[:,128:256) bf16
        int t = b * 256 + tid;                  // < 1.6M exactly
        int n = t >> 4, c8 = (t & 15) * 8;
        const float4* p = (const float4*)&x[(size_t)n * D + c8];
        float4 v0 = p[0], v1 = p[1];
        uint4 o;
        o.x = (unsigned)f2bf(v0.x) | ((unsigned)f2bf(v0.y) << 16);
        o.y = (unsigned)f2bf(v0.z) | ((unsigned)f2bf(v0.w) << 16);
        o.z = (unsigned)f2bf(v1.x) | ((unsigned)f2bf(v1.y) << 16);
        o.w = (unsigned)f2bf(v1.z) | ((unsigned)f2bf(v1.w) << 16);
        *(uint4*)&Amat[(size_t)n * K2 + 128 + c8] = o;
    } else if (b < CONV_BLOCKS + ZERO_BLOCKS) {
        int t = (b - CONV_BLOCKS) * 256 + tid;
        if (t < N_NODES / 4) counts4[t] = make_uint4(0, 0, 0, 0);
    } else {
        // wprep: pack [Wrel;Wroot] into MFMA B-fragment order, bf16.
        int slot = (b - CONV_BLOCKS - ZERO_BLOCKS) * 256 + tid;
        if (slot < 4096) {
            int lane = slot & 63;
            int ks = (slot >> 6) & 7;
            int ct = slot >> 9;
            int m = ct * 16 + (lane & 15);
            int k = ks * 32 + (lane >> 4) * 8;
            const float* src = (k < 128) ? &Wrel[(size_t)m * 128 + k]
                                         : &Wroot[(size_t)m * 128 + (k - 128)];
            uint4 o;
            o.x = (unsigned)f2bf(src[0]) | ((unsigned)f2bf(src[1]) << 16);
            o.y = (unsigned)f2bf(src[2]) | ((unsigned)f2bf(src[3]) << 16);
            o.z = (unsigned)f2bf(src[4]) | ((unsigned)f2bf(src[5]) << 16);
            o.w = (unsigned)f2bf(src[6]) | ((unsigned)f2bf(src[7]) << 16);
            *(uint4*)&Wfrag[(size_t)slot * 8] = o;
        }
    }
}

// ---------------------------------------------------------------------------
// Counting sort: hist -> 3-phase scan -> scatter_idx
// ---------------------------------------------------------------------------
__global__ void hist_kernel(const int* __restrict__ ei, int* __restrict__ counts) {
    int e = blockIdx.x * blockDim.x + threadIdx.x;
    if (e >= N_EDGES) return;
    atomicAdd(&counts[ei[N_EDGES + e]], 1);
}

__global__ __launch_bounds__(SCAN_TILE) void tile_sum_kernel(
        const int* __restrict__ counts, int* __restrict__ blockSums) {
    __shared__ int sh[SCAN_TILE];
    int t = threadIdx.x;
    int gid = blockIdx.x * SCAN_TILE + t;
    sh[t] = (gid < N_NODES) ? counts[gid] : 0;
    __syncthreads();
    for (int off = SCAN_TILE / 2; off > 0; off >>= 1) {
        if (t < off) sh[t] += sh[t + off];
        __syncthreads();
    }
    if (t == 0) blockSums[blockIdx.x] = sh[0];
}

__global__ void scan_blocks_kernel(const int* __restrict__ blockSums,
                                   int* __restrict__ blockOff) {
    __shared__ int sh[128];
    int t = threadIdx.x;
    int v = (t < NBLK) ? blockSums[t] : 0;
    sh[t] = v;
    __syncthreads();
    for (int off = 1; off < 128; off <<= 1) {
        int u = (t >= off) ? sh[t - off] : 0;
        __syncthreads();
        sh[t] += u;
        __syncthreads();
    }
    if (t < NBLK) blockOff[t] = sh[t] - v;
}

__global__ __launch_bounds__(SCAN_TILE) void scan_tile_kernel(
        const int* __restrict__ counts, const int* __restrict__ blockOff,
        int* __restrict__ offsets, int* __restrict__ cursor) {
    __shared__ int sh[SCAN_TILE];
    int t = threadIdx.x;
    int gid = blockIdx.x * SCAN_TILE + t;
    int v = (gid < N_NODES) ? counts[gid] : 0;
    sh[t] = v;
    __syncthreads();
    for (int off = 1; off < SCAN_TILE; off <<= 1) {
        int u = (t >= off) ? sh[t - off] : 0;
        __syncthreads();
        sh[t] += u;
        __syncthreads();
    }
    int excl = sh[t] - v + blockOff[blockIdx.x];
    if (gid < N_NODES) {
        offsets[gid] = excl;
        cursor[gid] = excl;
    }
    if (gid == N_NODES - 1) offsets[N_NODES] = excl + v;
}

__global__ void scatter_idx_kernel(const int* __restrict__ ei,
                                   int* __restrict__ cursor,
                                   int* __restrict__ srcSorted) {
    int e = blockIdx.x * blockDim.x + threadIdx.x;
    if (e >= N_EDGES) return;
    int s = ei[e];
    int t = ei[N_EDGES + e];
    int pos = atomicAdd(&cursor[t], 1);
    srcSorted[pos] = s;
}

// ---------------------------------------------------------------------------
// seg_sum v2: one wave per node; lanes 0-31 edge p, lanes 32-63 edge p+1;
// 2 gathers in flight per half; halves combined via shfl_xor(32).
// ---------------------------------------------------------------------------
__global__ void seg_sum_kernel(const int* __restrict__ offsets,
                               const int* __restrict__ srcSorted,
                               unsigned short* __restrict__ Amat) {
    int wid = (blockIdx.x * blockDim.x + threadIdx.x) >> 6;
    if (wid >= N_NODES) return;
    int lane = threadIdx.x & 63;
    int half = lane >> 5;
    int cq = (lane & 31) * 4;           // 4 bf16 cols = 8 B per lane
    int beg = offsets[wid], end = offsets[wid + 1];
    float4 acc = make_float4(0.f, 0.f, 0.f, 0.f);
    int p = beg + half;
    for (; p + 2 < end; p += 4) {
        int s0 = srcSorted[p], s1 = srcSorted[p + 2];
        uint2 u0 = *(const uint2*)&Amat[(size_t)s0 * K2 + 128 + cq];
        uint2 u1 = *(const uint2*)&Amat[(size_t)s1 * K2 + 128 + cq];
        acc.x += bf_lo(u0.x) + bf_lo(u1.x);
        acc.y += bf_hi(u0.x) + bf_hi(u1.x);
        acc.z += bf_lo(u0.y) + bf_lo(u1.y);
        acc.w += bf_hi(u0.y) + bf_hi(u1.y);
    }
    if (p < end) {
        int s0 = srcSorted[p];
        uint2 u0 = *(const uint2*)&Amat[(size_t)s0 * K2 + 128 + cq];
        acc.x += bf_lo(u0.x);
        acc.y += bf_hi(u0.x);
        acc.z += bf_lo(u0.y);
        acc.w += bf_hi(u0.y);
    }
    acc.x += __shfl_xor(acc.x, 32);
    acc.y += __shfl_xor(acc.y, 32);
    acc.z += __shfl_xor(acc.z, 32);
    acc.w += __shfl_xor(acc.w, 32);
    if (half == 0) {
        uint2 o;
        o.x = (unsigned)f2bf(acc.x) | ((unsigned)f2bf(acc.y) << 16);
        o.y = (unsigned)f2bf(acc.z) | ((unsigned)f2bf(acc.w) << 16);
        *(uint2*)&Amat[(size_t)wid * K2 + cq] = o;
    }
}

// ---------------------------------------------------------------------------
// gemm_mfma v3: 512 threads / 8 waves / 256 rows per block (391 blocks).
// Same 64 KB W-LDS -> 2 blocks/CU -> 16 waves/CU (4/SIMD, 2x v2).
// A preloaded in two K=128 halves (32 VGPR) to fit 128-VGPR budget.
// Epilogue: two 128-row swizzled-LDS transpose passes reusing W space.
// ---------------------------------------------------------------------------
__global__ __launch_bounds__(512, 4) void gemm_mfma(
        const unsigned short* __restrict__ Amat,
        const unsigned short* __restrict__ Wfrag,
        const float* __restrict__ brel,
        float* __restrict__ out) {
    __shared__ __align__(16) char smem[65536];
    short8* Wlds = (short8*)smem;
    float*  So   = (float*)smem;

    int tid = threadIdx.x;
    for (int i = tid; i < 4096; i += 512)
        Wlds[i] = *(const short8*)&Wfrag[(size_t)i * 8];
    __syncthreads();

    int lane = tid & 63;
    int w = tid >> 6;                    // 0..7
    int n16 = lane & 15, kg = lane >> 4;
    long rowB = (long)blockIdx.x * 256;
    long row0 = rowB + w * 32;

    long r0 = row0 + n16;
    long r1 = row0 + 16 + n16;
    long cr0 = (r0 < N_NODES) ? r0 : (N_NODES - 1);
    long cr1 = (r1 < N_NODES) ? r1 : (N_NODES - 1);
    const short8* a0p = (const short8*)(Amat + cr0 * K2 + kg * 8);
    const short8* a1p = (const short8*)(Amat + cr1 * K2 + kg * 8);

    f32x4 acc[2][8];
#pragma unroll
    for (int h = 0; h < 2; ++h)
#pragma unroll
        for (int ct = 0; ct < 8; ++ct)
            acc[h][ct] = (f32x4){0.f, 0.f, 0.f, 0.f};

    // ---- K half 1: ks 0..3 (8 loads in flight) ----
    short8 a0v[4], a1v[4];
#pragma unroll
    for (int k = 0; k < 4; ++k) { a0v[k] = a0p[k * 4]; a1v[k] = a1p[k * 4]; }
#pragma unroll
    for (int ks = 0; ks < 4; ++ks) {
#pragma unroll
        for (int ct = 0; ct < 8; ++ct) {
            short8 b = Wlds[(ct * 8 + ks) * 64 + lane];
            acc[0][ct] = __builtin_amdgcn_mfma_f32_16x16x32_bf16(a0v[ks], b, acc[0][ct], 0, 0, 0);
            acc[1][ct] = __builtin_amdgcn_mfma_f32_16x16x32_bf16(a1v[ks], b, acc[1][ct], 0, 0, 0);
        }
    }
    // ---- K half 2: ks 4..7 (loads overlap tail of half-1 MFMAs) ----
#pragma unroll
    for (int k = 0; k < 4; ++k) { a0v[k] = a0p[(k + 4) * 4]; a1v[k] = a1p[(k + 4) * 4]; }
#pragma unroll
    for (int ks = 4; ks < 8; ++ks) {
#pragma unroll
        for (int ct = 0; ct < 8; ++ct) {
            short8 b = Wlds[(ct * 8 + ks) * 64 + lane];
            acc[0][ct] = __builtin_amdgcn_mfma_f32_16x16x32_bf16(a0v[ks - 4], b, acc[0][ct], 0, 0, 0);
            acc[1][ct] = __builtin_amdgcn_mfma_f32_16x16x32_bf16(a1v[ks - 4], b, acc[1][ct], 0, 0, 0);
        }
    }

    __syncthreads();   // all waves done reading Wlds
    // D layout (m89): col = lane&15, row = 4*(lane>>4) + reg.
    // Pass 0: waves 0-3 stage rows 0..127; all threads store.
#pragma unroll
    for (int pass = 0; pass < 2; ++pass) {
        if ((w >> 2) == pass) {
            int wl = w & 3;
#pragma unroll
            for (int h = 0; h < 2; ++h)
#pragma unroll
                for (int ct = 0; ct < 8; ++ct) {
                    float bias = brel[ct * 16 + n16];
#pragma unroll
                    for (int r = 0; r < 4; ++r) {
                        int lrow = wl * 32 + h * 16 + kg * 4 + r;
                        int col = ct * 16 + n16;
                        So[lrow * 128 + (col ^ ((lrow & 7) << 2))] = acc[h][ct][r] + bias;
                    }
                }
        }
        __syncthreads();
#pragma unroll
        for (int j = 0; j < 8; ++j) {
            int g = tid + j * 512;
            int lrow = g >> 5;
            int q = g & 31;
            long grow = rowB + pass * 128 + lrow;
            if (grow < N_NODES) {
                float4 v = *(float4*)&So[lrow * 128 + ((q * 4) ^ ((lrow & 7) << 2))];
                *(float4*)&out[grow * 128 + q * 4] = v;
            }
        }
        __syncthreads();
    }
}

// ---------------------------------------------------------------------------
// Fallback (ws too small): atomic scatter + fp32 GEMM (round-1 path).
// ---------------------------------------------------------------------------
__global__ void scatter_kernel(const float* __restrict__ x,
                               const int* __restrict__ ei,
                               float* __restrict__ agg) {
    int gid = blockIdx.x * blockDim.x + threadIdx.x;
    int e = gid >> 5;
    if (e >= N_EDGES) return;
    int q = (gid & 31) * 4;
    int s = ei[e];
    int t = ei[N_EDGES + e];
    float4 v = *(const float4*)&x[(size_t)s * D + q];
    float* ap = &agg[(size_t)t * D + q];
    atomicAdd(ap + 0, v.x);
    atomicAdd(ap + 1, v.y);
    atomicAdd(ap + 2, v.z);
    atomicAdd(ap + 3, v.w);
}

__global__ __launch_bounds__(256, 1) void fused_gemm(
        const float* __restrict__ agg, const float* __restrict__ x,
        const float* __restrict__ Wrel, const float* __restrict__ brel,
        const float* __restrict__ Wroot, float* __restrict__ out,
        int nChunks) {
    __shared__ float W2t[256][128];
    __shared__ float rows[16][256];
    int tid = threadIdx.x;
    for (int idx = tid; idx < 256 * 128; idx += 256) {
        int k = idx >> 7, m = idx & 127;
        W2t[k][m] = (k < 128) ? Wrel[m * 128 + k] : Wroot[m * 128 + (k - 128)];
    }
    __syncthreads();
    int mq = tid & 31, rg = tid >> 5, m4 = mq * 4;
    for (int chunk = blockIdx.x; chunk < nChunks; chunk += gridDim.x) {
        size_t row0 = (size_t)chunk * 16;
        __syncthreads();
        for (int j = 0; j < 4; ++j) {
            int i = (tid + j * 256) * 4;
            int r = i >> 8, c = i & 255;
            float4 v;
            if (c < 128) v = *(const float4*)&agg[(row0 + r) * D + c];
            else         v = *(const float4*)&x[(row0 + r) * D + (c - 128)];
            *(float4*)&rows[r][c] = v;
        }
        __syncthreads();
        float4 acc0 = make_float4(0, 0, 0, 0), acc1 = make_float4(0, 0, 0, 0);
#pragma unroll 8
        for (int k = 0; k < 256; ++k) {
            float4 wv = *(const float4*)&W2t[k][m4];
            float A0 = rows[rg][k], A1 = rows[rg + 8][k];
            acc0.x = fmaf(A0, wv.x, acc0.x); acc0.y = fmaf(A0, wv.y, acc0.y);
            acc0.z = fmaf(A0, wv.z, acc0.z); acc0.w = fmaf(A0, wv.w, acc0.w);
            acc1.x = fmaf(A1, wv.x, acc1.x); acc1.y = fmaf(A1, wv.y, acc1.y);
            acc1.z = fmaf(A1, wv.z, acc1.z); acc1.w = fmaf(A1, wv.w, acc1.w);
        }
        float4 b = *(const float4*)&brel[m4];
        *(float4*)&out[(row0 + rg) * D + m4] =
            make_float4(acc0.x + b.x, acc0.y + b.y, acc0.z + b.z, acc0.w + b.w);
        *(float4*)&out[(row0 + rg + 8) * D + m4] =
            make_float4(acc1.x + b.x, acc1.y + b.y, acc1.z + b.z, acc1.w + b.w);
    }
}

extern "C" void kernel_launch(void* const* d_in, const int* in_sizes, int n_in,
                              void* d_out, int out_size, void* d_ws, size_t ws_size,
                              hipStream_t stream) {
    const float* x     = (const float*)d_in[0];
    const int*   ei    = (const int*)d_in[1];
    const float* Wrel  = (const float*)d_in[2];
    const float* brel  = (const float*)d_in[3];
    const float* Wroot = (const float*)d_in[4];
    float* out = (float*)d_out;

    const size_t amatBytes = (size_t)N_NODES * K2 * sizeof(unsigned short); // 51.2 MB
    const size_t offBytes  = (size_t)(N_NODES + 1) * sizeof(int);
    const size_t curBytes  = (size_t)N_NODES * sizeof(int);
    const size_t srcBytes  = (size_t)N_EDGES * sizeof(int);
    const size_t cntBytes  = (size_t)N_NODES * sizeof(int);
    const size_t blkBytes  = (size_t)NBLK * sizeof(int);
    const size_t wfBytes   = (size_t)4096 * 8 * sizeof(unsigned short);     // 64 KB
    auto align16 = [](size_t v) { return (v + 15) & ~(size_t)15; };

    size_t o_amat = 0;
    size_t o_off  = align16(o_amat + amatBytes);
    size_t o_cur  = align16(o_off + offBytes);
    size_t o_src  = align16(o_cur + curBytes);
    size_t o_cnt  = align16(o_src + srcBytes);
    size_t o_bs   = align16(o_cnt + cntBytes);
    size_t o_bo   = align16(o_bs + blkBytes);
    size_t o_wf   = align16(o_bo + blkBytes);
    size_t total  = o_wf + wfBytes;

    if (ws_size >= total) {
        char* ws = (char*)d_ws;
        unsigned short* Amat  = (unsigned short*)(ws + o_amat);
        int*   offsets   = (int*)(ws + o_off);
        int*   cursor    = (int*)(ws + o_cur);
        int*   srcSorted = (int*)(ws + o_src);
        int*   counts    = (int*)(ws + o_cnt);
        int*   blockSums = (int*)(ws + o_bs);
        int*   blockOff  = (int*)(ws + o_bo);
        unsigned short* Wfrag = (unsigned short*)(ws + o_wf);

        prep_kernel<<<CONV_BLOCKS + ZERO_BLOCKS + WPREP_BLOCKS, 256, 0, stream>>>(
            x, Amat, (uint4*)counts, Wrel, Wroot, Wfrag);
        hist_kernel<<<(N_EDGES + 255) / 256, 256, 0, stream>>>(ei, counts);
        tile_sum_kernel<<<NBLK, SCAN_TILE, 0, stream>>>(counts, blockSums);
        scan_blocks_kernel<<<1, 128, 0, stream>>>(blockSums, blockOff);
        scan_tile_kernel<<<NBLK, SCAN_TILE, 0, stream>>>(counts, blockOff, offsets, cursor);
        scatter_idx_kernel<<<(N_EDGES + 255) / 256, 256, 0, stream>>>(ei, cursor, srcSorted);
        seg_sum_kernel<<<(N_NODES * 64 + 255) / 256, 256, 0, stream>>>(offsets, srcSorted, Amat);
        gemm_mfma<<<(N_NODES + 255) / 256, 512, 0, stream>>>(Amat, Wfrag, brel, out);
    } else {
        // Fallback: atomic scatter + fp32 GEMM.
        float* agg = (ws_size >= (size_t)N_NODES * D * sizeof(float)) ? (float*)d_ws : out;
        hipMemsetAsync(agg, 0, (size_t)N_NODES * D * sizeof(float), stream);
        scatter_kernel<<<(N_EDGES * 32 + 255) / 256, 256, 0, stream>>>(x, ei, agg);
        fused_gemm<<<256, 256, 0, stream>>>(agg, x, Wrel, brel, Wroot, out,
                                            N_NODES / 16);
    }
}

// Round 9
// 109.964 us; speedup vs baseline: 1.4567x; 1.2842x over previous
//
#include <hip/hip_runtime.h>

#define N_NODES 100000
#define N_EDGES 600000
#define D 128
#define K2 256          // stacked K = [agg | x]

#define NBUCKET 196        // ceil(N_NODES / 512); bucket = dst >> 9
#define SB_EPT 8
#define SB_EDGES (256 * SB_EPT)                          // 2048 edges/block
#define SB_BLOCKS ((N_EDGES + SB_EDGES - 1) / SB_EDGES)  // 293

#define CONV_BLOCKS 6250   // N_NODES*16 / 256 exactly
#define WPREP_BLOCKS 16    // 4096 slots / 256

typedef __attribute__((ext_vector_type(8))) short short8;
typedef __attribute__((ext_vector_type(4))) float f32x4;

__device__ __forceinline__ unsigned short f2bf(float f) {
    union { float f; unsigned u; } v; v.f = f;
    unsigned u = v.u;
    u += 0x7FFFu + ((u >> 16) & 1u);     // round-to-nearest-even
    return (unsigned short)(u >> 16);
}

__device__ __forceinline__ float bf_lo(unsigned u) {
    union { unsigned u; float f; } v; v.u = u << 16; return v.f;
}
__device__ __forceinline__ float bf_hi(unsigned u) {
    union { unsigned u; float f; } v; v.u = u & 0xFFFF0000u; return v.f;
}

// ---------------------------------------------------------------------------
// prep: fused {convert_x | wprep | zero bucketCount}.
// ---------------------------------------------------------------------------
__global__ void prep_kernel(const float* __restrict__ x,
                            unsigned short* __restrict__ Amat,
                            const float* __restrict__ Wrel,
                            const float* __restrict__ Wroot,
                            unsigned short* __restrict__ Wfrag,
                            int* __restrict__ bucketCount) {
    int b = blockIdx.x;
    int tid = threadIdx.x;
    if (b < CONV_BLOCKS) {
        // convert_x: x fp32 -> Amat[:,128:256) bf16
        int t = b * 256 + tid;                  // < 1.6M exactly
        int n = t >> 4, c8 = (t & 15) * 8;
        const float4* p = (const float4*)&x[(size_t)n * D + c8];
        float4 v0 = p[0], v1 = p[1];
        uint4 o;
        o.x = (unsigned)f2bf(v0.x) | ((unsigned)f2bf(v0.y) << 16);
        o.y = (unsigned)f2bf(v0.z) | ((unsigned)f2bf(v0.w) << 16);
        o.z = (unsigned)f2bf(v1.x) | ((unsigned)f2bf(v1.y) << 16);
        o.w = (unsigned)f2bf(v1.z) | ((unsigned)f2bf(v1.w) << 16);
        *(uint4*)&Amat[(size_t)n * K2 + 128 + c8] = o;
    } else if (b < CONV_BLOCKS + WPREP_BLOCKS) {
        // wprep: pack [Wrel;Wroot] into MFMA B-fragment order, bf16.
        int slot = (b - CONV_BLOCKS) * 256 + tid;   // < 4096 exactly
        int lane = slot & 63;
        int ks = (slot >> 6) & 7;
        int ct = slot >> 9;
        int m = ct * 16 + (lane & 15);
        int k = ks * 32 + (lane >> 4) * 8;
        const float* src = (k < 128) ? &Wrel[(size_t)m * 128 + k]
                                     : &Wroot[(size_t)m * 128 + (k - 128)];
        uint4 o;
        o.x = (unsigned)f2bf(src[0]) | ((unsigned)f2bf(src[1]) << 16);
        o.y = (unsigned)f2bf(src[2]) | ((unsigned)f2bf(src[3]) << 16);
        o.z = (unsigned)f2bf(src[4]) | ((unsigned)f2bf(src[5]) << 16);
        o.w = (unsigned)f2bf(src[6]) | ((unsigned)f2bf(src[7]) << 16);
        *(uint4*)&Wfrag[(size_t)slot * 8] = o;
    } else {
        if (tid < NBUCKET) bucketCount[tid] = 0;
    }
}

// ---------------------------------------------------------------------------
// bucket_hist: LDS-aggregated histogram over 196 dst-buckets.
// 600K edges -> 196*293 = 57K global atomics (vs 600K), no line ping-pong.
// ---------------------------------------------------------------------------
__global__ __launch_bounds__(256) void bucket_hist_kernel(
        const int* __restrict__ ei, int* __restrict__ bucketCount) {
    __shared__ int cnt[NBUCKET];
    int tid = threadIdx.x;
    for (int i = tid; i < NBUCKET; i += 256) cnt[i] = 0;
    __syncthreads();
    int e0 = blockIdx.x * SB_EDGES + tid;
#pragma unroll
    for (int j = 0; j < SB_EPT; ++j) {
        int e = e0 + j * 256;
        if (e < N_EDGES) atomicAdd(&cnt[ei[N_EDGES + e] >> 9], 1);
    }
    __syncthreads();
    for (int i = tid; i < NBUCKET; i += 256)
        if (cnt[i]) atomicAdd(&bucketCount[i], cnt[i]);
}

// ---------------------------------------------------------------------------
// bucket_scan: exclusive scan of 196 bucket counts (one tiny block);
// writes bucketBase[197] and initializes bucketCursor.
// ---------------------------------------------------------------------------
__global__ void bucket_scan_kernel(const int* __restrict__ bucketCount,
                                   int* __restrict__ bucketBase,
                                   int* __restrict__ bucketCursor) {
    __shared__ int sh[256];
    int t = threadIdx.x;
    int v = (t < NBUCKET) ? bucketCount[t] : 0;
    sh[t] = v;
    __syncthreads();
    for (int off = 1; off < 256; off <<= 1) {
        int u = (t >= off) ? sh[t - off] : 0;
        __syncthreads();
        sh[t] += u;
        __syncthreads();
    }
    if (t < NBUCKET) {
        int excl = sh[t] - v;
        bucketBase[t] = excl;
        bucketCursor[t] = excl;
    }
    if (t == 0) bucketBase[NBUCKET] = N_EDGES;
}

// ---------------------------------------------------------------------------
// bucket_scatter: partition edges into dst-buckets.  Per-block LDS ranking,
// ONE cursor atomic per (block,bucket); packed payload (dst&511)<<17 | src
// written to each bucket's contiguous region (write runs, not random 4B).
// ---------------------------------------------------------------------------
__global__ __launch_bounds__(256) void bucket_scatter_kernel(
        const int* __restrict__ ei, int* __restrict__ bucketCursor,
        unsigned* __restrict__ edgeTmp) {
    __shared__ int cnt[NBUCKET];
    __shared__ int base[NBUCKET];
    int tid = threadIdx.x;
    for (int i = tid; i < NBUCKET; i += 256) cnt[i] = 0;
    __syncthreads();
    int e0 = blockIdx.x * SB_EDGES + tid;
    unsigned pack[SB_EPT];
    int bk[SB_EPT], rk[SB_EPT];
#pragma unroll
    for (int j = 0; j < SB_EPT; ++j) {
        int e = e0 + j * 256;
        if (e < N_EDGES) {
            int s = ei[e];
            int d = ei[N_EDGES + e];
            pack[j] = (unsigned)s | ((unsigned)(d & 511) << 17);
            bk[j] = d >> 9;
            rk[j] = atomicAdd(&cnt[bk[j]], 1);
        } else bk[j] = -1;
    }
    __syncthreads();
    for (int i = tid; i < NBUCKET; i += 256)
        base[i] = cnt[i] ? atomicAdd(&bucketCursor[i], cnt[i]) : 0;
    __syncthreads();
#pragma unroll
    for (int j = 0; j < SB_EPT; ++j)
        if (bk[j] >= 0)
            edgeTmp[base[bk[j]] + rk[j]] = pack[j];
}

// ---------------------------------------------------------------------------
// bucket_finalize: one block per bucket (512 dsts, ~12KB edge region, fully
// L2-local).  LDS count of local dsts -> LDS scan -> writes offsets[] AND
// the final dst-sorted srcSorted[].
// ---------------------------------------------------------------------------
__global__ __launch_bounds__(256) void bucket_finalize_kernel(
        const unsigned* __restrict__ edgeTmp, const int* __restrict__ bucketBase,
        int* __restrict__ offsets, int* __restrict__ srcSorted) {
    __shared__ int cnt[512];
    __shared__ int cur[512];
    __shared__ int sh[256];
    int b = blockIdx.x, tid = threadIdx.x;
    int d0 = b << 9;
    cnt[tid] = 0; cnt[tid + 256] = 0;
    __syncthreads();
    int beg = bucketBase[b], end = bucketBase[b + 1];
    for (int i = beg + tid; i < end; i += 256)
        atomicAdd(&cnt[edgeTmp[i] >> 17], 1);
    __syncthreads();
    // exclusive scan of 512 counts: pair-sum -> H-S over 256 -> expand
    int c0 = cnt[2 * tid], c1 = cnt[2 * tid + 1];
    int ps = c0 + c1;
    sh[tid] = ps;
    __syncthreads();
    for (int off = 1; off < 256; off <<= 1) {
        int u = (tid >= off) ? sh[tid - off] : 0;
        __syncthreads();
        sh[tid] += u;
        __syncthreads();
    }
    int pexcl = sh[tid] - ps + beg;
    cur[2 * tid] = pexcl;
    cur[2 * tid + 1] = pexcl + c0;
    int d = d0 + 2 * tid;
    if (d < N_NODES) offsets[d] = pexcl;
    if (d + 1 < N_NODES) offsets[d + 1] = pexcl + c0;
    __syncthreads();
    for (int i = beg + tid; i < end; i += 256) {
        unsigned p = edgeTmp[i];
        int pos = atomicAdd(&cur[p >> 17], 1);
        srcSorted[pos] = (int)(p & 0x1FFFFu);
    }
    if (b == 0 && tid == 0) offsets[N_NODES] = N_EDGES;
}

// ---------------------------------------------------------------------------
// seg_sum: one wave per node; lanes 0-31 edge p, lanes 32-63 edge p+1;
// 2 gathers in flight per half; halves combined via shfl_xor(32).
// ---------------------------------------------------------------------------
__global__ void seg_sum_kernel(const int* __restrict__ offsets,
                               const int* __restrict__ srcSorted,
                               unsigned short* __restrict__ Amat) {
    int wid = (blockIdx.x * blockDim.x + threadIdx.x) >> 6;
    if (wid >= N_NODES) return;
    int lane = threadIdx.x & 63;
    int half = lane >> 5;
    int cq = (lane & 31) * 4;           // 4 bf16 cols = 8 B per lane
    int beg = offsets[wid], end = offsets[wid + 1];
    float4 acc = make_float4(0.f, 0.f, 0.f, 0.f);
    int p = beg + half;
    for (; p + 2 < end; p += 4) {
        int s0 = srcSorted[p], s1 = srcSorted[p + 2];
        uint2 u0 = *(const uint2*)&Amat[(size_t)s0 * K2 + 128 + cq];
        uint2 u1 = *(const uint2*)&Amat[(size_t)s1 * K2 + 128 + cq];
        acc.x += bf_lo(u0.x) + bf_lo(u1.x);
        acc.y += bf_hi(u0.x) + bf_hi(u1.x);
        acc.z += bf_lo(u0.y) + bf_lo(u1.y);
        acc.w += bf_hi(u0.y) + bf_hi(u1.y);
    }
    if (p < end) {
        int s0 = srcSorted[p];
        uint2 u0 = *(const uint2*)&Amat[(size_t)s0 * K2 + 128 + cq];
        acc.x += bf_lo(u0.x);
        acc.y += bf_hi(u0.x);
        acc.z += bf_lo(u0.y);
        acc.w += bf_hi(u0.y);
    }
    acc.x += __shfl_xor(acc.x, 32);
    acc.y += __shfl_xor(acc.y, 32);
    acc.z += __shfl_xor(acc.z, 32);
    acc.w += __shfl_xor(acc.w, 32);
    if (half == 0) {
        uint2 o;
        o.x = (unsigned)f2bf(acc.x) | ((unsigned)f2bf(acc.y) << 16);
        o.y = (unsigned)f2bf(acc.z) | ((unsigned)f2bf(acc.w) << 16);
        *(uint2*)&Amat[(size_t)wid * K2 + cq] = o;
    }
}

// ---------------------------------------------------------------------------
// gemm_mfma v3: 512 threads / 8 waves / 256 rows per block (391 blocks).
// ---------------------------------------------------------------------------
__global__ __launch_bounds__(512, 4) void gemm_mfma(
        const unsigned short* __restrict__ Amat,
        const unsigned short* __restrict__ Wfrag,
        const float* __restrict__ brel,
        float* __restrict__ out) {
    __shared__ __align__(16) char smem[65536];
    short8* Wlds = (short8*)smem;
    float*  So   = (float*)smem;

    int tid = threadIdx.x;
    for (int i = tid; i < 4096; i += 512)
        Wlds[i] = *(const short8*)&Wfrag[(size_t)i * 8];
    __syncthreads();

    int lane = tid & 63;
    int w = tid >> 6;                    // 0..7
    int n16 = lane & 15, kg = lane >> 4;
    long rowB = (long)blockIdx.x * 256;
    long row0 = rowB + w * 32;

    long r0 = row0 + n16;
    long r1 = row0 + 16 + n16;
    long cr0 = (r0 < N_NODES) ? r0 : (N_NODES - 1);
    long cr1 = (r1 < N_NODES) ? r1 : (N_NODES - 1);
    const short8* a0p = (const short8*)(Amat + cr0 * K2 + kg * 8);
    const short8* a1p = (const short8*)(Amat + cr1 * K2 + kg * 8);

    f32x4 acc[2][8];
#pragma unroll
    for (int h = 0; h < 2; ++h)
#pragma unroll
        for (int ct = 0; ct < 8; ++ct)
            acc[h][ct] = (f32x4){0.f, 0.f, 0.f, 0.f};

    short8 a0v[4], a1v[4];
#pragma unroll
    for (int k = 0; k < 4; ++k) { a0v[k] = a0p[k * 4]; a1v[k] = a1p[k * 4]; }
#pragma unroll
    for (int ks = 0; ks < 4; ++ks) {
#pragma unroll
        for (int ct = 0; ct < 8; ++ct) {
            short8 b = Wlds[(ct * 8 + ks) * 64 + lane];
            acc[0][ct] = __builtin_amdgcn_mfma_f32_16x16x32_bf16(a0v[ks], b, acc[0][ct], 0, 0, 0);
            acc[1][ct] = __builtin_amdgcn_mfma_f32_16x16x32_bf16(a1v[ks], b, acc[1][ct], 0, 0, 0);
        }
    }
#pragma unroll
    for (int k = 0; k < 4; ++k) { a0v[k] = a0p[(k + 4) * 4]; a1v[k] = a1p[(k + 4) * 4]; }
#pragma unroll
    for (int ks = 4; ks < 8; ++ks) {
#pragma unroll
        for (int ct = 0; ct < 8; ++ct) {
            short8 b = Wlds[(ct * 8 + ks) * 64 + lane];
            acc[0][ct] = __builtin_amdgcn_mfma_f32_16x16x32_bf16(a0v[ks - 4], b, acc[0][ct], 0, 0, 0);
            acc[1][ct] = __builtin_amdgcn_mfma_f32_16x16x32_bf16(a1v[ks - 4], b, acc[1][ct], 0, 0, 0);
        }
    }

    __syncthreads();   // all waves done reading Wlds
    // D layout (m89): col = lane&15, row = 4*(lane>>4) + reg.
#pragma unroll
    for (int pass = 0; pass < 2; ++pass) {
        if ((w >> 2) == pass) {
            int wl = w & 3;
#pragma unroll
            for (int h = 0; h < 2; ++h)
#pragma unroll
                for (int ct = 0; ct < 8; ++ct) {
                    float bias = brel[ct * 16 + n16];
#pragma unroll
                    for (int r = 0; r < 4; ++r) {
                        int lrow = wl * 32 + h * 16 + kg * 4 + r;
                        int col = ct * 16 + n16;
                        So[lrow * 128 + (col ^ ((lrow & 7) << 2))] = acc[h][ct][r] + bias;
                    }
                }
        }
        __syncthreads();
#pragma unroll
        for (int j = 0; j < 8; ++j) {
            int g = tid + j * 512;
            int lrow = g >> 5;
            int q = g & 31;
            long grow = rowB + pass * 128 + lrow;
            if (grow < N_NODES) {
                float4 v = *(float4*)&So[lrow * 128 + ((q * 4) ^ ((lrow & 7) << 2))];
                *(float4*)&out[grow * 128 + q * 4] = v;
            }
        }
        __syncthreads();
    }
}

// ---------------------------------------------------------------------------
// Fallback (ws too small): atomic scatter + fp32 GEMM (round-1 path).
// ---------------------------------------------------------------------------
__global__ void scatter_kernel(const float* __restrict__ x,
                               const int* __restrict__ ei,
                               float* __restrict__ agg) {
    int gid = blockIdx.x * blockDim.x + threadIdx.x;
    int e = gid >> 5;
    if (e >= N_EDGES) return;
    int q = (gid & 31) * 4;
    int s = ei[e];
    int t = ei[N_EDGES + e];
    float4 v = *(const float4*)&x[(size_t)s * D + q];
    float* ap = &agg[(size_t)t * D + q];
    atomicAdd(ap + 0, v.x);
    atomicAdd(ap + 1, v.y);
    atomicAdd(ap + 2, v.z);
    atomicAdd(ap + 3, v.w);
}

__global__ __launch_bounds__(256, 1) void fused_gemm(
        const float* __restrict__ agg, const float* __restrict__ x,
        const float* __restrict__ Wrel, const float* __restrict__ brel,
        const float* __restrict__ Wroot, float* __restrict__ out,
        int nChunks) {
    __shared__ float W2t[256][128];
    __shared__ float rows[16][256];
    int tid = threadIdx.x;
    for (int idx = tid; idx < 256 * 128; idx += 256) {
        int k = idx >> 7, m = idx & 127;
        W2t[k][m] = (k < 128) ? Wrel[m * 128 + k] : Wroot[m * 128 + (k - 128)];
    }
    __syncthreads();
    int mq = tid & 31, rg = tid >> 5, m4 = mq * 4;
    for (int chunk = blockIdx.x; chunk < nChunks; chunk += gridDim.x) {
        size_t row0 = (size_t)chunk * 16;
        __syncthreads();
        for (int j = 0; j < 4; ++j) {
            int i = (tid + j * 256) * 4;
            int r = i >> 8, c = i & 255;
            float4 v;
            if (c < 128) v = *(const float4*)&agg[(row0 + r) * D + c];
            else         v = *(const float4*)&x[(row0 + r) * D + (c - 128)];
            *(float4*)&rows[r][c] = v;
        }
        __syncthreads();
        float4 acc0 = make_float4(0, 0, 0, 0), acc1 = make_float4(0, 0, 0, 0);
#pragma unroll 8
        for (int k = 0; k < 256; ++k) {
            float4 wv = *(const float4*)&W2t[k][m4];
            float A0 = rows[rg][k], A1 = rows[rg + 8][k];
            acc0.x = fmaf(A0, wv.x, acc0.x); acc0.y = fmaf(A0, wv.y, acc0.y);
            acc0.z = fmaf(A0, wv.z, acc0.z); acc0.w = fmaf(A0, wv.w, acc0.w);
            acc1.x = fmaf(A1, wv.x, acc1.x); acc1.y = fmaf(A1, wv.y, acc1.y);
            acc1.z = fmaf(A1, wv.z, acc1.z); acc1.w = fmaf(A1, wv.w, acc1.w);
        }
        float4 b = *(const float4*)&brel[m4];
        *(float4*)&out[(row0 + rg) * D + m4] =
            make_float4(acc0.x + b.x, acc0.y + b.y, acc0.z + b.z, acc0.w + b.w);
        *(float4*)&out[(row0 + rg + 8) * D + m4] =
            make_float4(acc1.x + b.x, acc1.y + b.y, acc1.z + b.z, acc1.w + b.w);
    }
}

extern "C" void kernel_launch(void* const* d_in, const int* in_sizes, int n_in,
                              void* d_out, int out_size, void* d_ws, size_t ws_size,
                              hipStream_t stream) {
    const float* x     = (const float*)d_in[0];
    const int*   ei    = (const int*)d_in[1];
    const float* Wrel  = (const float*)d_in[2];
    const float* brel  = (const float*)d_in[3];
    const float* Wroot = (const float*)d_in[4];
    float* out = (float*)d_out;

    const size_t amatBytes = (size_t)N_NODES * K2 * sizeof(unsigned short); // 51.2 MB
    const size_t offBytes  = (size_t)(N_NODES + 1) * sizeof(int);
    const size_t srcBytes  = (size_t)N_EDGES * sizeof(int);
    const size_t etmpBytes = (size_t)N_EDGES * sizeof(unsigned);
    const size_t bcntBytes = (size_t)NBUCKET * sizeof(int);
    const size_t bbasBytes = (size_t)(NBUCKET + 1) * sizeof(int);
    const size_t bcurBytes = (size_t)NBUCKET * sizeof(int);
    const size_t wfBytes   = (size_t)4096 * 8 * sizeof(unsigned short);     // 64 KB
    auto align16 = [](size_t v) { return (v + 15) & ~(size_t)15; };

    size_t o_amat = 0;
    size_t o_off  = align16(o_amat + amatBytes);
    size_t o_src  = align16(o_off + offBytes);
    size_t o_etmp = align16(o_src + srcBytes);
    size_t o_bcnt = align16(o_etmp + etmpBytes);
    size_t o_bbas = align16(o_bcnt + bcntBytes);
    size_t o_bcur = align16(o_bbas + bbasBytes);
    size_t o_wf   = align16(o_bcur + bcurBytes);
    size_t total  = o_wf + wfBytes;

    if (ws_size >= total) {
        char* ws = (char*)d_ws;
        unsigned short* Amat  = (unsigned short*)(ws + o_amat);
        int*      offsets     = (int*)(ws + o_off);
        int*      srcSorted   = (int*)(ws + o_src);
        unsigned* edgeTmp     = (unsigned*)(ws + o_etmp);
        int*      bucketCount = (int*)(ws + o_bcnt);
        int*      bucketBase  = (int*)(ws + o_bbas);
        int*      bucketCursor= (int*)(ws + o_bcur);
        unsigned short* Wfrag = (unsigned short*)(ws + o_wf);

        prep_kernel<<<CONV_BLOCKS + WPREP_BLOCKS + 1, 256, 0, stream>>>(
            x, Amat, Wrel, Wroot, Wfrag, bucketCount);
        bucket_hist_kernel<<<SB_BLOCKS, 256, 0, stream>>>(ei, bucketCount);
        bucket_scan_kernel<<<1, 256, 0, stream>>>(bucketCount, bucketBase, bucketCursor);
        bucket_scatter_kernel<<<SB_BLOCKS, 256, 0, stream>>>(ei, bucketCursor, edgeTmp);
        bucket_finalize_kernel<<<NBUCKET, 256, 0, stream>>>(edgeTmp, bucketBase,
                                                            offsets, srcSorted);
        seg_sum_kernel<<<(N_NODES * 64 + 255) / 256, 256, 0, stream>>>(offsets, srcSorted, Amat);
        gemm_mfma<<<(N_NODES + 255) / 256, 512, 0, stream>>>(Amat, Wfrag, brel, out);
    } else {
        // Fallback: atomic scatter + fp32 GEMM.
        float* agg = (ws_size >= (size_t)N_NODES * D * sizeof(float)) ? (float*)d_ws : out;
        hipMemsetAsync(agg, 0, (size_t)N_NODES * D * sizeof(float), stream);
        scatter_kernel<<<(N_EDGES * 32 + 255) / 256, 256, 0, stream>>>(x, ei, agg);
        fused_gemm<<<256, 256, 0, stream>>>(agg, x, Wrel, brel, Wroot, out,
                                            N_NODES / 16);
    }
}

// Round 10
// 101.727 us; speedup vs baseline: 1.5746x; 1.0810x over previous
//
#include <hip/hip_runtime.h>

#define N_NODES 100000
#define N_EDGES 600000
#define D 128
#define K2 256          // stacked K = [agg | x]

#define NBUCKET 196        // ceil(N_NODES / 512); bucket = dst >> 9
#define SB_EPT 8
#define SB_EDGES (256 * SB_EPT)                          // 2048 edges/block
#define SB_BLOCKS ((N_EDGES + SB_EDGES - 1) / SB_EDGES)  // 293

#define CONV_BLOCKS 6250   // N_NODES*16 / 256 exactly
#define WPREP_BLOCKS 16    // 4096 slots / 256

typedef __attribute__((ext_vector_type(8))) short short8;
typedef __attribute__((ext_vector_type(4))) float f32x4;

__device__ __forceinline__ unsigned short f2bf(float f) {
    union { float f; unsigned u; } v; v.f = f;
    unsigned u = v.u;
    u += 0x7FFFu + ((u >> 16) & 1u);     // round-to-nearest-even
    return (unsigned short)(u >> 16);
}

__device__ __forceinline__ float bf_lo(unsigned u) {
    union { unsigned u; float f; } v; v.u = u << 16; return v.f;
}
__device__ __forceinline__ float bf_hi(unsigned u) {
    union { unsigned u; float f; } v; v.u = u & 0xFFFF0000u; return v.f;
}

// ---------------------------------------------------------------------------
// prep: fused {convert_x | wprep | zero bucketCount+cursor0}.
// ---------------------------------------------------------------------------
__global__ void prep_kernel(const float* __restrict__ x,
                            unsigned short* __restrict__ Amat,
                            const float* __restrict__ Wrel,
                            const float* __restrict__ Wroot,
                            unsigned short* __restrict__ Wfrag,
                            int* __restrict__ bucketCount,
                            int* __restrict__ cursor0) {
    int b = blockIdx.x;
    int tid = threadIdx.x;
    if (b < CONV_BLOCKS) {
        // convert_x: x fp32 -> Amat[:,128:256) bf16
        int t = b * 256 + tid;                  // < 1.6M exactly
        int n = t >> 4, c8 = (t & 15) * 8;
        const float4* p = (const float4*)&x[(size_t)n * D + c8];
        float4 v0 = p[0], v1 = p[1];
        uint4 o;
        o.x = (unsigned)f2bf(v0.x) | ((unsigned)f2bf(v0.y) << 16);
        o.y = (unsigned)f2bf(v0.z) | ((unsigned)f2bf(v0.w) << 16);
        o.z = (unsigned)f2bf(v1.x) | ((unsigned)f2bf(v1.y) << 16);
        o.w = (unsigned)f2bf(v1.z) | ((unsigned)f2bf(v1.w) << 16);
        *(uint4*)&Amat[(size_t)n * K2 + 128 + c8] = o;
    } else if (b < CONV_BLOCKS + WPREP_BLOCKS) {
        // wprep: pack [Wrel;Wroot] into MFMA B-fragment order, bf16.
        int slot = (b - CONV_BLOCKS) * 256 + tid;   // < 4096 exactly
        int lane = slot & 63;
        int ks = (slot >> 6) & 7;
        int ct = slot >> 9;
        int m = ct * 16 + (lane & 15);
        int k = ks * 32 + (lane >> 4) * 8;
        const float* src = (k < 128) ? &Wrel[(size_t)m * 128 + k]
                                     : &Wroot[(size_t)m * 128 + (k - 128)];
        uint4 o;
        o.x = (unsigned)f2bf(src[0]) | ((unsigned)f2bf(src[1]) << 16);
        o.y = (unsigned)f2bf(src[2]) | ((unsigned)f2bf(src[3]) << 16);
        o.z = (unsigned)f2bf(src[4]) | ((unsigned)f2bf(src[5]) << 16);
        o.w = (unsigned)f2bf(src[6]) | ((unsigned)f2bf(src[7]) << 16);
        *(uint4*)&Wfrag[(size_t)slot * 8] = o;
    } else {
        if (tid < NBUCKET) { bucketCount[tid] = 0; cursor0[tid] = 0; }
    }
}

// ---------------------------------------------------------------------------
// bucket_hist: LDS-aggregated histogram over 196 dst-buckets.
// ---------------------------------------------------------------------------
__global__ __launch_bounds__(256) void bucket_hist_kernel(
        const int* __restrict__ ei, int* __restrict__ bucketCount) {
    __shared__ int cnt[NBUCKET];
    int tid = threadIdx.x;
    for (int i = tid; i < NBUCKET; i += 256) cnt[i] = 0;
    __syncthreads();
    int e0 = blockIdx.x * SB_EDGES + tid;
#pragma unroll
    for (int j = 0; j < SB_EPT; ++j) {
        int e = e0 + j * 256;
        if (e < N_EDGES) atomicAdd(&cnt[ei[N_EDGES + e] >> 9], 1);
    }
    __syncthreads();
    for (int i = tid; i < NBUCKET; i += 256)
        if (cnt[i]) atomicAdd(&bucketCount[i], cnt[i]);
}

// ---------------------------------------------------------------------------
// bucket_scatter: partition edges into dst-buckets.  The 196-bucket global
// scan is recomputed IN-BLOCK (kills the separate scan launch); reservation
// via zero-based cursor0 atomics.  Packed payload (dst&511)<<17 | src.
// ---------------------------------------------------------------------------
__global__ __launch_bounds__(256) void bucket_scatter_kernel(
        const int* __restrict__ ei, const int* __restrict__ bucketCount,
        int* __restrict__ cursor0, unsigned* __restrict__ edgeTmp) {
    __shared__ int cnt[NBUCKET];
    __shared__ int base[NBUCKET];
    __shared__ int gbase[NBUCKET];
    __shared__ int sh[256];
    int tid = threadIdx.x;
    int v = (tid < NBUCKET) ? bucketCount[tid] : 0;
    sh[tid] = v;
    for (int i = tid; i < NBUCKET; i += 256) cnt[i] = 0;
    __syncthreads();
    for (int off = 1; off < 256; off <<= 1) {
        int u = (tid >= off) ? sh[tid - off] : 0;
        __syncthreads();
        sh[tid] += u;
        __syncthreads();
    }
    if (tid < NBUCKET) gbase[tid] = sh[tid] - v;   // global exclusive base
    __syncthreads();

    int e0 = blockIdx.x * SB_EDGES + tid;
    unsigned pack[SB_EPT];
    int bk[SB_EPT], rk[SB_EPT];
#pragma unroll
    for (int j = 0; j < SB_EPT; ++j) {
        int e = e0 + j * 256;
        if (e < N_EDGES) {
            int s = ei[e];
            int d = ei[N_EDGES + e];
            pack[j] = (unsigned)s | ((unsigned)(d & 511) << 17);
            bk[j] = d >> 9;
            rk[j] = atomicAdd(&cnt[bk[j]], 1);
        } else bk[j] = -1;
    }
    __syncthreads();
    for (int i = tid; i < NBUCKET; i += 256)
        base[i] = cnt[i] ? gbase[i] + atomicAdd(&cursor0[i], cnt[i]) : 0;
    __syncthreads();
#pragma unroll
    for (int j = 0; j < SB_EPT; ++j)
        if (bk[j] >= 0)
            edgeTmp[base[bk[j]] + rk[j]] = pack[j];
}

// ---------------------------------------------------------------------------
// bucket_finalize: one block per bucket.  Recomputes the 196-scan in-block
// for beg/end, then LDS count/scan of 512 local dsts -> offsets + srcSorted.
// ---------------------------------------------------------------------------
__global__ __launch_bounds__(256) void bucket_finalize_kernel(
        const unsigned* __restrict__ edgeTmp, const int* __restrict__ bucketCount,
        int* __restrict__ offsets, int* __restrict__ srcSorted) {
    __shared__ int cnt[512];
    __shared__ int cur[512];
    __shared__ int sh[256];
    __shared__ int begend[2];
    int b = blockIdx.x, tid = threadIdx.x;
    // 196-scan for this bucket's [beg,end)
    int v = (tid < NBUCKET) ? bucketCount[tid] : 0;
    sh[tid] = v;
    cnt[tid] = 0; cnt[tid + 256] = 0;
    __syncthreads();
    for (int off = 1; off < 256; off <<= 1) {
        int u = (tid >= off) ? sh[tid - off] : 0;
        __syncthreads();
        sh[tid] += u;
        __syncthreads();
    }
    if (tid == 0) begend[0] = (b > 0) ? sh[b - 1] : 0;
    if (tid == 1) begend[1] = sh[b];
    __syncthreads();
    int beg = begend[0], end = begend[1];
    int d0 = b << 9;
    for (int i = beg + tid; i < end; i += 256)
        atomicAdd(&cnt[edgeTmp[i] >> 17], 1);
    __syncthreads();
    // exclusive scan of 512 counts: pair-sum -> H-S over 256 -> expand
    int c0 = cnt[2 * tid], c1 = cnt[2 * tid + 1];
    int ps = c0 + c1;
    sh[tid] = ps;
    __syncthreads();
    for (int off = 1; off < 256; off <<= 1) {
        int u = (tid >= off) ? sh[tid - off] : 0;
        __syncthreads();
        sh[tid] += u;
        __syncthreads();
    }
    int pexcl = sh[tid] - ps + beg;
    cur[2 * tid] = pexcl;
    cur[2 * tid + 1] = pexcl + c0;
    int d = d0 + 2 * tid;
    if (d < N_NODES) offsets[d] = pexcl;
    if (d + 1 < N_NODES) offsets[d + 1] = pexcl + c0;
    __syncthreads();
    for (int i = beg + tid; i < end; i += 256) {
        unsigned p = edgeTmp[i];
        int pos = atomicAdd(&cur[p >> 17], 1);
        srcSorted[pos] = (int)(p & 0x1FFFFu);
    }
    if (b == 0 && tid == 0) offsets[N_NODES] = N_EDGES;
}

// ---------------------------------------------------------------------------
// seg_sum v3: quarter-wave gather.  16 lanes x 16B = one full 256B bf16 row
// per load instruction; 4 nodes per wave; 2 edges in flight per quarter
// (8 x 256B = 2KB in flight per wave, 4x v2's MLP).  Full-lane utilization
// regardless of odd degrees; no shfl combine; coalesced uint4 write-out.
// ---------------------------------------------------------------------------
__global__ void seg_sum_kernel(const int* __restrict__ offsets,
                               const int* __restrict__ srcSorted,
                               unsigned short* __restrict__ Amat) {
    int wave = (blockIdx.x * blockDim.x + threadIdx.x) >> 6;
    int lane = threadIdx.x & 63;
    int node = wave * 4 + (lane >> 4);
    if (node >= N_NODES) return;
    int c8 = (lane & 15) * 8;          // 8 bf16 cols = 16 B per lane
    int beg = offsets[node], end = offsets[node + 1];
    float a0 = 0, a1 = 0, a2 = 0, a3 = 0, a4 = 0, a5 = 0, a6 = 0, a7 = 0;
    int p = beg;
    for (; p + 1 < end; p += 2) {
        int s0 = srcSorted[p], s1 = srcSorted[p + 1];   // quarter-uniform
        uint4 u0 = *(const uint4*)&Amat[(size_t)s0 * K2 + 128 + c8];
        uint4 u1 = *(const uint4*)&Amat[(size_t)s1 * K2 + 128 + c8];
        a0 += bf_lo(u0.x) + bf_lo(u1.x);
        a1 += bf_hi(u0.x) + bf_hi(u1.x);
        a2 += bf_lo(u0.y) + bf_lo(u1.y);
        a3 += bf_hi(u0.y) + bf_hi(u1.y);
        a4 += bf_lo(u0.z) + bf_lo(u1.z);
        a5 += bf_hi(u0.z) + bf_hi(u1.z);
        a6 += bf_lo(u0.w) + bf_lo(u1.w);
        a7 += bf_hi(u0.w) + bf_hi(u1.w);
    }
    if (p < end) {
        int s0 = srcSorted[p];
        uint4 u0 = *(const uint4*)&Amat[(size_t)s0 * K2 + 128 + c8];
        a0 += bf_lo(u0.x); a1 += bf_hi(u0.x);
        a2 += bf_lo(u0.y); a3 += bf_hi(u0.y);
        a4 += bf_lo(u0.z); a5 += bf_hi(u0.z);
        a6 += bf_lo(u0.w); a7 += bf_hi(u0.w);
    }
    uint4 o;
    o.x = (unsigned)f2bf(a0) | ((unsigned)f2bf(a1) << 16);
    o.y = (unsigned)f2bf(a2) | ((unsigned)f2bf(a3) << 16);
    o.z = (unsigned)f2bf(a4) | ((unsigned)f2bf(a5) << 16);
    o.w = (unsigned)f2bf(a6) | ((unsigned)f2bf(a7) << 16);
    *(uint4*)&Amat[(size_t)node * K2 + c8] = o;
}

// ---------------------------------------------------------------------------
// gemm_mfma v3: 512 threads / 8 waves / 256 rows per block (391 blocks).
// ---------------------------------------------------------------------------
__global__ __launch_bounds__(512, 4) void gemm_mfma(
        const unsigned short* __restrict__ Amat,
        const unsigned short* __restrict__ Wfrag,
        const float* __restrict__ brel,
        float* __restrict__ out) {
    __shared__ __align__(16) char smem[65536];
    short8* Wlds = (short8*)smem;
    float*  So   = (float*)smem;

    int tid = threadIdx.x;
    for (int i = tid; i < 4096; i += 512)
        Wlds[i] = *(const short8*)&Wfrag[(size_t)i * 8];
    __syncthreads();

    int lane = tid & 63;
    int w = tid >> 6;                    // 0..7
    int n16 = lane & 15, kg = lane >> 4;
    long rowB = (long)blockIdx.x * 256;
    long row0 = rowB + w * 32;

    long r0 = row0 + n16;
    long r1 = row0 + 16 + n16;
    long cr0 = (r0 < N_NODES) ? r0 : (N_NODES - 1);
    long cr1 = (r1 < N_NODES) ? r1 : (N_NODES - 1);
    const short8* a0p = (const short8*)(Amat + cr0 * K2 + kg * 8);
    const short8* a1p = (const short8*)(Amat + cr1 * K2 + kg * 8);

    f32x4 acc[2][8];
#pragma unroll
    for (int h = 0; h < 2; ++h)
#pragma unroll
        for (int ct = 0; ct < 8; ++ct)
            acc[h][ct] = (f32x4){0.f, 0.f, 0.f, 0.f};

    short8 a0v[4], a1v[4];
#pragma unroll
    for (int k = 0; k < 4; ++k) { a0v[k] = a0p[k * 4]; a1v[k] = a1p[k * 4]; }
#pragma unroll
    for (int ks = 0; ks < 4; ++ks) {
#pragma unroll
        for (int ct = 0; ct < 8; ++ct) {
            short8 b = Wlds[(ct * 8 + ks) * 64 + lane];
            acc[0][ct] = __builtin_amdgcn_mfma_f32_16x16x32_bf16(a0v[ks], b, acc[0][ct], 0, 0, 0);
            acc[1][ct] = __builtin_amdgcn_mfma_f32_16x16x32_bf16(a1v[ks], b, acc[1][ct], 0, 0, 0);
        }
    }
#pragma unroll
    for (int k = 0; k < 4; ++k) { a0v[k] = a0p[(k + 4) * 4]; a1v[k] = a1p[(k + 4) * 4]; }
#pragma unroll
    for (int ks = 4; ks < 8; ++ks) {
#pragma unroll
        for (int ct = 0; ct < 8; ++ct) {
            short8 b = Wlds[(ct * 8 + ks) * 64 + lane];
            acc[0][ct] = __builtin_amdgcn_mfma_f32_16x16x32_bf16(a0v[ks - 4], b, acc[0][ct], 0, 0, 0);
            acc[1][ct] = __builtin_amdgcn_mfma_f32_16x16x32_bf16(a1v[ks - 4], b, acc[1][ct], 0, 0, 0);
        }
    }

    __syncthreads();   // all waves done reading Wlds
    // D layout (m89): col = lane&15, row = 4*(lane>>4) + reg.
#pragma unroll
    for (int pass = 0; pass < 2; ++pass) {
        if ((w >> 2) == pass) {
            int wl = w & 3;
#pragma unroll
            for (int h = 0; h < 2; ++h)
#pragma unroll
                for (int ct = 0; ct < 8; ++ct) {
                    float bias = brel[ct * 16 + n16];
#pragma unroll
                    for (int r = 0; r < 4; ++r) {
                        int lrow = wl * 32 + h * 16 + kg * 4 + r;
                        int col = ct * 16 + n16;
                        So[lrow * 128 + (col ^ ((lrow & 7) << 2))] = acc[h][ct][r] + bias;
                    }
                }
        }
        __syncthreads();
#pragma unroll
        for (int j = 0; j < 8; ++j) {
            int g = tid + j * 512;
            int lrow = g >> 5;
            int q = g & 31;
            long grow = rowB + pass * 128 + lrow;
            if (grow < N_NODES) {
                float4 v = *(float4*)&So[lrow * 128 + ((q * 4) ^ ((lrow & 7) << 2))];
                *(float4*)&out[grow * 128 + q * 4] = v;
            }
        }
        __syncthreads();
    }
}

// ---------------------------------------------------------------------------
// Fallback (ws too small): atomic scatter + fp32 GEMM (round-1 path).
// ---------------------------------------------------------------------------
__global__ void scatter_kernel(const float* __restrict__ x,
                               const int* __restrict__ ei,
                               float* __restrict__ agg) {
    int gid = blockIdx.x * blockDim.x + threadIdx.x;
    int e = gid >> 5;
    if (e >= N_EDGES) return;
    int q = (gid & 31) * 4;
    int s = ei[e];
    int t = ei[N_EDGES + e];
    float4 v = *(const float4*)&x[(size_t)s * D + q];
    float* ap = &agg[(size_t)t * D + q];
    atomicAdd(ap + 0, v.x);
    atomicAdd(ap + 1, v.y);
    atomicAdd(ap + 2, v.z);
    atomicAdd(ap + 3, v.w);
}

__global__ __launch_bounds__(256, 1) void fused_gemm(
        const float* __restrict__ agg, const float* __restrict__ x,
        const float* __restrict__ Wrel, const float* __restrict__ brel,
        const float* __restrict__ Wroot, float* __restrict__ out,
        int nChunks) {
    __shared__ float W2t[256][128];
    __shared__ float rows[16][256];
    int tid = threadIdx.x;
    for (int idx = tid; idx < 256 * 128; idx += 256) {
        int k = idx >> 7, m = idx & 127;
        W2t[k][m] = (k < 128) ? Wrel[m * 128 + k] : Wroot[m * 128 + (k - 128)];
    }
    __syncthreads();
    int mq = tid & 31, rg = tid >> 5, m4 = mq * 4;
    for (int chunk = blockIdx.x; chunk < nChunks; chunk += gridDim.x) {
        size_t row0 = (size_t)chunk * 16;
        __syncthreads();
        for (int j = 0; j < 4; ++j) {
            int i = (tid + j * 256) * 4;
            int r = i >> 8, c = i & 255;
            float4 v;
            if (c < 128) v = *(const float4*)&agg[(row0 + r) * D + c];
            else         v = *(const float4*)&x[(row0 + r) * D + (c - 128)];
            *(float4*)&rows[r][c] = v;
        }
        __syncthreads();
        float4 acc0 = make_float4(0, 0, 0, 0), acc1 = make_float4(0, 0, 0, 0);
#pragma unroll 8
        for (int k = 0; k < 256; ++k) {
            float4 wv = *(const float4*)&W2t[k][m4];
            float A0 = rows[rg][k], A1 = rows[rg + 8][k];
            acc0.x = fmaf(A0, wv.x, acc0.x); acc0.y = fmaf(A0, wv.y, acc0.y);
            acc0.z = fmaf(A0, wv.z, acc0.z); acc0.w = fmaf(A0, wv.w, acc0.w);
            acc1.x = fmaf(A1, wv.x, acc1.x); acc1.y = fmaf(A1, wv.y, acc1.y);
            acc1.z = fmaf(A1, wv.z, acc1.z); acc1.w = fmaf(A1, wv.w, acc1.w);
        }
        float4 b = *(const float4*)&brel[m4];
        *(float4*)&out[(row0 + rg) * D + m4] =
            make_float4(acc0.x + b.x, acc0.y + b.y, acc0.z + b.z, acc0.w + b.w);
        *(float4*)&out[(row0 + rg + 8) * D + m4] =
            make_float4(acc1.x + b.x, acc1.y + b.y, acc1.z + b.z, acc1.w + b.w);
    }
}

extern "C" void kernel_launch(void* const* d_in, const int* in_sizes, int n_in,
                              void* d_out, int out_size, void* d_ws, size_t ws_size,
                              hipStream_t stream) {
    const float* x     = (const float*)d_in[0];
    const int*   ei    = (const int*)d_in[1];
    const float* Wrel  = (const float*)d_in[2];
    const float* brel  = (const float*)d_in[3];
    const float* Wroot = (const float*)d_in[4];
    float* out = (float*)d_out;

    const size_t amatBytes = (size_t)N_NODES * K2 * sizeof(unsigned short); // 51.2 MB
    const size_t offBytes  = (size_t)(N_NODES + 1) * sizeof(int);
    const size_t srcBytes  = (size_t)N_EDGES * sizeof(int);
    const size_t etmpBytes = (size_t)N_EDGES * sizeof(unsigned);
    const size_t bcntBytes = (size_t)NBUCKET * sizeof(int);
    const size_t bcurBytes = (size_t)NBUCKET * sizeof(int);
    const size_t wfBytes   = (size_t)4096 * 8 * sizeof(unsigned short);     // 64 KB
    auto align16 = [](size_t v) { return (v + 15) & ~(size_t)15; };

    size_t o_amat = 0;
    size_t o_off  = align16(o_amat + amatBytes);
    size_t o_src  = align16(o_off + offBytes);
    size_t o_etmp = align16(o_src + srcBytes);
    size_t o_bcnt = align16(o_etmp + etmpBytes);
    size_t o_bcur = align16(o_bcnt + bcntBytes);
    size_t o_wf   = align16(o_bcur + bcurBytes);
    size_t total  = o_wf + wfBytes;

    if (ws_size >= total) {
        char* ws = (char*)d_ws;
        unsigned short* Amat  = (unsigned short*)(ws + o_amat);
        int*      offsets     = (int*)(ws + o_off);
        int*      srcSorted   = (int*)(ws + o_src);
        unsigned* edgeTmp     = (unsigned*)(ws + o_etmp);
        int*      bucketCount = (int*)(ws + o_bcnt);
        int*      cursor0     = (int*)(ws + o_bcur);
        unsigned short* Wfrag = (unsigned short*)(ws + o_wf);

        prep_kernel<<<CONV_BLOCKS + WPREP_BLOCKS + 1, 256, 0, stream>>>(
            x, Amat, Wrel, Wroot, Wfrag, bucketCount, cursor0);
        bucket_hist_kernel<<<SB_BLOCKS, 256, 0, stream>>>(ei, bucketCount);
        bucket_scatter_kernel<<<SB_BLOCKS, 256, 0, stream>>>(ei, bucketCount,
                                                             cursor0, edgeTmp);
        bucket_finalize_kernel<<<NBUCKET, 256, 0, stream>>>(edgeTmp, bucketCount,
                                                            offsets, srcSorted);
        seg_sum_kernel<<<(N_NODES / 4 * 64 + 255) / 256, 256, 0, stream>>>(
            offsets, srcSorted, Amat);
        gemm_mfma<<<(N_NODES + 255) / 256, 512, 0, stream>>>(Amat, Wfrag, brel, out);
    } else {
        // Fallback: atomic scatter + fp32 GEMM.
        float* agg = (ws_size >= (size_t)N_NODES * D * sizeof(float)) ? (float*)d_ws : out;
        hipMemsetAsync(agg, 0, (size_t)N_NODES * D * sizeof(float), stream);
        scatter_kernel<<<(N_EDGES * 32 + 255) / 256, 256, 0, stream>>>(x, ei, agg);
        fused_gemm<<<256, 256, 0, stream>>>(agg, x, Wrel, brel, Wroot, out,
                                            N_NODES / 16);
    }
}

// Round 11
// 89.600 us; speedup vs baseline: 1.7877x; 1.1353x over previous
//
#include <hip/hip_runtime.h>

#define N_NODES 100000
#define N_EDGES 600000
#define D 128
#define K2 256          // stacked K = [agg | x]

#define NBUCKET 196        // ceil(N_NODES / 512); bucket = dst >> 9
#define SB_EPT 8
#define SB_EDGES (256 * SB_EPT)                          // 2048 edges/block
#define SB_BLOCKS ((N_EDGES + SB_EDGES - 1) / SB_EDGES)  // 293
#define CAPB 4608          // padded per-bucket capacity (mean 3072, sigma~55)

#define CONV_BLOCKS 6250   // N_NODES*16 / 256 exactly
#define WPREP_BLOCKS 16    // 4096 slots / 256

typedef __attribute__((ext_vector_type(8))) short short8;
typedef __attribute__((ext_vector_type(4))) float f32x4;

__device__ __forceinline__ unsigned short f2bf(float f) {
    union { float f; unsigned u; } v; v.f = f;
    unsigned u = v.u;
    u += 0x7FFFu + ((u >> 16) & 1u);     // round-to-nearest-even
    return (unsigned short)(u >> 16);
}

__device__ __forceinline__ float bf_lo(unsigned u) {
    union { unsigned u; float f; } v; v.u = u << 16; return v.f;
}
__device__ __forceinline__ float bf_hi(unsigned u) {
    union { unsigned u; float f; } v; v.u = u & 0xFFFF0000u; return v.f;
}

// ---------------------------------------------------------------------------
// mega: fused {convert_x | wprep | local_sort}.  All three block families
// are mutually independent (local_sort needs NO global state: each block
// writes its own edgeTmp region + per-block bucket offset table).
// ---------------------------------------------------------------------------
__global__ __launch_bounds__(256) void mega_kernel(
        const float* __restrict__ x,
        unsigned short* __restrict__ Amat,
        const float* __restrict__ Wrel,
        const float* __restrict__ Wroot,
        unsigned short* __restrict__ Wfrag,
        const int* __restrict__ ei,
        unsigned* __restrict__ edgeTmp,
        int* __restrict__ blockBucketOff) {
    __shared__ int cnt[NBUCKET];
    __shared__ int pos[NBUCKET];
    __shared__ int sh[256];
    int b = blockIdx.x;
    int tid = threadIdx.x;
    if (b < CONV_BLOCKS) {
        // convert_x: x fp32 -> Amat[:,128:256) bf16
        int t = b * 256 + tid;                  // < 1.6M exactly
        int n = t >> 4, c8 = (t & 15) * 8;
        const float4* p = (const float4*)&x[(size_t)n * D + c8];
        float4 v0 = p[0], v1 = p[1];
        uint4 o;
        o.x = (unsigned)f2bf(v0.x) | ((unsigned)f2bf(v0.y) << 16);
        o.y = (unsigned)f2bf(v0.z) | ((unsigned)f2bf(v0.w) << 16);
        o.z = (unsigned)f2bf(v1.x) | ((unsigned)f2bf(v1.y) << 16);
        o.w = (unsigned)f2bf(v1.z) | ((unsigned)f2bf(v1.w) << 16);
        *(uint4*)&Amat[(size_t)n * K2 + 128 + c8] = o;
    } else if (b < CONV_BLOCKS + WPREP_BLOCKS) {
        // wprep: pack [Wrel;Wroot] into MFMA B-fragment order, bf16.
        int slot = (b - CONV_BLOCKS) * 256 + tid;   // < 4096 exactly
        int lane = slot & 63;
        int ks = (slot >> 6) & 7;
        int ct = slot >> 9;
        int m = ct * 16 + (lane & 15);
        int k = ks * 32 + (lane >> 4) * 8;
        const float* src = (k < 128) ? &Wrel[(size_t)m * 128 + k]
                                     : &Wroot[(size_t)m * 128 + (k - 128)];
        uint4 o;
        o.x = (unsigned)f2bf(src[0]) | ((unsigned)f2bf(src[1]) << 16);
        o.y = (unsigned)f2bf(src[2]) | ((unsigned)f2bf(src[3]) << 16);
        o.z = (unsigned)f2bf(src[4]) | ((unsigned)f2bf(src[5]) << 16);
        o.w = (unsigned)f2bf(src[6]) | ((unsigned)f2bf(src[7]) << 16);
        *(uint4*)&Wfrag[(size_t)slot * 8] = o;
    } else {
        // local_sort: bucket-group this block's 2048 edges into its OWN
        // edgeTmp region; write per-block bucket offsets (197 ints).
        int sb = b - CONV_BLOCKS - WPREP_BLOCKS;
        for (int i = tid; i < NBUCKET; i += 256) cnt[i] = 0;
        __syncthreads();
        int e0 = sb * SB_EDGES + tid;
        unsigned pack[SB_EPT];
        int bk[SB_EPT], rk[SB_EPT];
#pragma unroll
        for (int j = 0; j < SB_EPT; ++j) {
            int e = e0 + j * 256;
            if (e < N_EDGES) {
                int s = ei[e];
                int d = ei[N_EDGES + e];
                pack[j] = (unsigned)s | ((unsigned)(d & 511) << 17);
                bk[j] = d >> 9;
                rk[j] = atomicAdd(&cnt[bk[j]], 1);
            } else bk[j] = -1;
        }
        __syncthreads();
        int v = (tid < NBUCKET) ? cnt[tid] : 0;
        sh[tid] = v;
        __syncthreads();
        for (int off = 1; off < 256; off <<= 1) {
            int u = (tid >= off) ? sh[tid - off] : 0;
            __syncthreads();
            sh[tid] += u;
            __syncthreads();
        }
        int excl = sh[tid] - v;             // tid==196 -> total valid count
        if (tid < NBUCKET) pos[tid] = excl;
        if (tid <= NBUCKET) blockBucketOff[sb * (NBUCKET + 1) + tid] = excl;
        __syncthreads();
#pragma unroll
        for (int j = 0; j < SB_EPT; ++j)
            if (bk[j] >= 0)
                edgeTmp[sb * SB_EDGES + pos[bk[j]] + rk[j]] = pack[j];
    }
}

// ---------------------------------------------------------------------------
// finalize: one block per bucket k.  Gathers the 293 per-block runs of
// bucket k into LDS staging, counts/scans the 512 local dsts, writes
// per-node (beg,end) into offs2 and srcs into PADDED srcSortedPad[k*CAPB..].
// No global scan anywhere.
// ---------------------------------------------------------------------------
__global__ __launch_bounds__(256) void finalize_kernel(
        const unsigned* __restrict__ edgeTmp,
        const int* __restrict__ blockBucketOff,
        int* __restrict__ offs2, int* __restrict__ srcSortedPad) {
    __shared__ unsigned eLDS[CAPB];      // 18 KB staging
    __shared__ int bs[512], bn[512], bp[512];
    __shared__ int cnt[512], cur[512];
    __shared__ int sh[256];
    int k = blockIdx.x, tid = threadIdx.x;

    // per-source-block run begin/count for this bucket
    for (int b = tid; b < 512; b += 256) { bn[b] = 0; bs[b] = 0; }
    cnt[tid] = 0; cnt[tid + 256] = 0;
    __syncthreads();
    for (int b = tid; b < SB_BLOCKS; b += 256) {
        int s = blockBucketOff[b * (NBUCKET + 1) + k];
        int e = blockBucketOff[b * (NBUCKET + 1) + k + 1];
        bs[b] = s;
        bn[b] = e - s;
    }
    __syncthreads();
    // exclusive scan of 512 run-counts (pair trick)
    int c0 = bn[2 * tid], c1 = bn[2 * tid + 1];
    int ps = c0 + c1;
    sh[tid] = ps;
    __syncthreads();
    for (int off = 1; off < 256; off <<= 1) {
        int u = (tid >= off) ? sh[tid - off] : 0;
        __syncthreads();
        sh[tid] += u;
        __syncthreads();
    }
    int pexcl = sh[tid] - ps;
    bp[2 * tid] = pexcl;
    bp[2 * tid + 1] = pexcl + c0;
    __syncthreads();
    int total = bp[511] + bn[511];
    if (total > CAPB) total = CAPB;      // statistically impossible; safety
    // copy runs into staging
    for (int b = tid; b < SB_BLOCKS; b += 256) {
        int s = bs[b], n = bn[b], dp = bp[b];
        for (int i = 0; i < n; ++i)
            if (dp + i < CAPB)
                eLDS[dp + i] = edgeTmp[b * SB_EDGES + s + i];
    }
    __syncthreads();
    // count local dsts
    for (int i = tid; i < total; i += 256)
        atomicAdd(&cnt[eLDS[i] >> 17], 1);
    __syncthreads();
    // exclusive scan of 512 dst-counts (pair trick)
    c0 = cnt[2 * tid]; c1 = cnt[2 * tid + 1];
    ps = c0 + c1;
    sh[tid] = ps;
    __syncthreads();
    for (int off = 1; off < 256; off <<= 1) {
        int u = (tid >= off) ? sh[tid - off] : 0;
        __syncthreads();
        sh[tid] += u;
        __syncthreads();
    }
    int base = k * CAPB;
    pexcl = sh[tid] - ps + base;
    cur[2 * tid] = pexcl;
    cur[2 * tid + 1] = pexcl + c0;
    int d = (k << 9) + 2 * tid;
    if (d < N_NODES) {
        offs2[2 * d] = pexcl;
        offs2[2 * d + 1] = pexcl + c0;
    }
    if (d + 1 < N_NODES) {
        offs2[2 * d + 2] = pexcl + c0;
        offs2[2 * d + 3] = pexcl + c0 + c1;
    }
    __syncthreads();
    for (int i = tid; i < total; i += 256) {
        unsigned p = eLDS[i];
        int posn = atomicAdd(&cur[p >> 17], 1);
        srcSortedPad[posn] = (int)(p & 0x1FFFFu);
    }
}

// ---------------------------------------------------------------------------
// seg_sum v4: quarter-wave gather (16 lanes x 16B = one 256B bf16 row per
// instruction); 4 nodes/wave; 2 edges in flight/quarter; per-node (beg,end)
// from offs2 (padded layout -- no cross-bucket contiguity needed).
// ---------------------------------------------------------------------------
__global__ void seg_sum_kernel(const int* __restrict__ offs2,
                               const int* __restrict__ srcSortedPad,
                               unsigned short* __restrict__ Amat) {
    int wave = (blockIdx.x * blockDim.x + threadIdx.x) >> 6;
    int lane = threadIdx.x & 63;
    int node = wave * 4 + (lane >> 4);
    if (node >= N_NODES) return;
    int c8 = (lane & 15) * 8;          // 8 bf16 cols = 16 B per lane
    int2 be = *(const int2*)&offs2[2 * node];
    int beg = be.x, end = be.y;
    float a0 = 0, a1 = 0, a2 = 0, a3 = 0, a4 = 0, a5 = 0, a6 = 0, a7 = 0;
    int p = beg;
    for (; p + 1 < end; p += 2) {
        int s0 = srcSortedPad[p], s1 = srcSortedPad[p + 1];
        uint4 u0 = *(const uint4*)&Amat[(size_t)s0 * K2 + 128 + c8];
        uint4 u1 = *(const uint4*)&Amat[(size_t)s1 * K2 + 128 + c8];
        a0 += bf_lo(u0.x) + bf_lo(u1.x);
        a1 += bf_hi(u0.x) + bf_hi(u1.x);
        a2 += bf_lo(u0.y) + bf_lo(u1.y);
        a3 += bf_hi(u0.y) + bf_hi(u1.y);
        a4 += bf_lo(u0.z) + bf_lo(u1.z);
        a5 += bf_hi(u0.z) + bf_hi(u1.z);
        a6 += bf_lo(u0.w) + bf_lo(u1.w);
        a7 += bf_hi(u0.w) + bf_hi(u1.w);
    }
    if (p < end) {
        int s0 = srcSortedPad[p];
        uint4 u0 = *(const uint4*)&Amat[(size_t)s0 * K2 + 128 + c8];
        a0 += bf_lo(u0.x); a1 += bf_hi(u0.x);
        a2 += bf_lo(u0.y); a3 += bf_hi(u0.y);
        a4 += bf_lo(u0.z); a5 += bf_hi(u0.z);
        a6 += bf_lo(u0.w); a7 += bf_hi(u0.w);
    }
    uint4 o;
    o.x = (unsigned)f2bf(a0) | ((unsigned)f2bf(a1) << 16);
    o.y = (unsigned)f2bf(a2) | ((unsigned)f2bf(a3) << 16);
    o.z = (unsigned)f2bf(a4) | ((unsigned)f2bf(a5) << 16);
    o.w = (unsigned)f2bf(a6) | ((unsigned)f2bf(a7) << 16);
    *(uint4*)&Amat[(size_t)node * K2 + c8] = o;
}

// ---------------------------------------------------------------------------
// gemm_mfma v3: 512 threads / 8 waves / 256 rows per block (391 blocks).
// ---------------------------------------------------------------------------
__global__ __launch_bounds__(512, 4) void gemm_mfma(
        const unsigned short* __restrict__ Amat,
        const unsigned short* __restrict__ Wfrag,
        const float* __restrict__ brel,
        float* __restrict__ out) {
    __shared__ __align__(16) char smem[65536];
    short8* Wlds = (short8*)smem;
    float*  So   = (float*)smem;

    int tid = threadIdx.x;
    for (int i = tid; i < 4096; i += 512)
        Wlds[i] = *(const short8*)&Wfrag[(size_t)i * 8];
    __syncthreads();

    int lane = tid & 63;
    int w = tid >> 6;                    // 0..7
    int n16 = lane & 15, kg = lane >> 4;
    long rowB = (long)blockIdx.x * 256;
    long row0 = rowB + w * 32;

    long r0 = row0 + n16;
    long r1 = row0 + 16 + n16;
    long cr0 = (r0 < N_NODES) ? r0 : (N_NODES - 1);
    long cr1 = (r1 < N_NODES) ? r1 : (N_NODES - 1);
    const short8* a0p = (const short8*)(Amat + cr0 * K2 + kg * 8);
    const short8* a1p = (const short8*)(Amat + cr1 * K2 + kg * 8);

    f32x4 acc[2][8];
#pragma unroll
    for (int h = 0; h < 2; ++h)
#pragma unroll
        for (int ct = 0; ct < 8; ++ct)
            acc[h][ct] = (f32x4){0.f, 0.f, 0.f, 0.f};

    short8 a0v[4], a1v[4];
#pragma unroll
    for (int k = 0; k < 4; ++k) { a0v[k] = a0p[k * 4]; a1v[k] = a1p[k * 4]; }
#pragma unroll
    for (int ks = 0; ks < 4; ++ks) {
#pragma unroll
        for (int ct = 0; ct < 8; ++ct) {
            short8 b = Wlds[(ct * 8 + ks) * 64 + lane];
            acc[0][ct] = __builtin_amdgcn_mfma_f32_16x16x32_bf16(a0v[ks], b, acc[0][ct], 0, 0, 0);
            acc[1][ct] = __builtin_amdgcn_mfma_f32_16x16x32_bf16(a1v[ks], b, acc[1][ct], 0, 0, 0);
        }
    }
#pragma unroll
    for (int k = 0; k < 4; ++k) { a0v[k] = a0p[(k + 4) * 4]; a1v[k] = a1p[(k + 4) * 4]; }
#pragma unroll
    for (int ks = 4; ks < 8; ++ks) {
#pragma unroll
        for (int ct = 0; ct < 8; ++ct) {
            short8 b = Wlds[(ct * 8 + ks) * 64 + lane];
            acc[0][ct] = __builtin_amdgcn_mfma_f32_16x16x32_bf16(a0v[ks - 4], b, acc[0][ct], 0, 0, 0);
            acc[1][ct] = __builtin_amdgcn_mfma_f32_16x16x32_bf16(a1v[ks - 4], b, acc[1][ct], 0, 0, 0);
        }
    }

    __syncthreads();   // all waves done reading Wlds
    // D layout (m89): col = lane&15, row = 4*(lane>>4) + reg.
#pragma unroll
    for (int pass = 0; pass < 2; ++pass) {
        if ((w >> 2) == pass) {
            int wl = w & 3;
#pragma unroll
            for (int h = 0; h < 2; ++h)
#pragma unroll
                for (int ct = 0; ct < 8; ++ct) {
                    float bias = brel[ct * 16 + n16];
#pragma unroll
                    for (int r = 0; r < 4; ++r) {
                        int lrow = wl * 32 + h * 16 + kg * 4 + r;
                        int col = ct * 16 + n16;
                        So[lrow * 128 + (col ^ ((lrow & 7) << 2))] = acc[h][ct][r] + bias;
                    }
                }
        }
        __syncthreads();
#pragma unroll
        for (int j = 0; j < 8; ++j) {
            int g = tid + j * 512;
            int lrow = g >> 5;
            int q = g & 31;
            long grow = rowB + pass * 128 + lrow;
            if (grow < N_NODES) {
                float4 v = *(float4*)&So[lrow * 128 + ((q * 4) ^ ((lrow & 7) << 2))];
                *(float4*)&out[grow * 128 + q * 4] = v;
            }
        }
        __syncthreads();
    }
}

// ---------------------------------------------------------------------------
// Fallback (ws too small): atomic scatter + fp32 GEMM (round-1 path).
// ---------------------------------------------------------------------------
__global__ void scatter_kernel(const float* __restrict__ x,
                               const int* __restrict__ ei,
                               float* __restrict__ agg) {
    int gid = blockIdx.x * blockDim.x + threadIdx.x;
    int e = gid >> 5;
    if (e >= N_EDGES) return;
    int q = (gid & 31) * 4;
    int s = ei[e];
    int t = ei[N_EDGES + e];
    float4 v = *(const float4*)&x[(size_t)s * D + q];
    float* ap = &agg[(size_t)t * D + q];
    atomicAdd(ap + 0, v.x);
    atomicAdd(ap + 1, v.y);
    atomicAdd(ap + 2, v.z);
    atomicAdd(ap + 3, v.w);
}

__global__ __launch_bounds__(256, 1) void fused_gemm(
        const float* __restrict__ agg, const float* __restrict__ x,
        const float* __restrict__ Wrel, const float* __restrict__ brel,
        const float* __restrict__ Wroot, float* __restrict__ out,
        int nChunks) {
    __shared__ float W2t[256][128];
    __shared__ float rows[16][256];
    int tid = threadIdx.x;
    for (int idx = tid; idx < 256 * 128; idx += 256) {
        int k = idx >> 7, m = idx & 127;
        W2t[k][m] = (k < 128) ? Wrel[m * 128 + k] : Wroot[m * 128 + (k - 128)];
    }
    __syncthreads();
    int mq = tid & 31, rg = tid >> 5, m4 = mq * 4;
    for (int chunk = blockIdx.x; chunk < nChunks; chunk += gridDim.x) {
        size_t row0 = (size_t)chunk * 16;
        __syncthreads();
        for (int j = 0; j < 4; ++j) {
            int i = (tid + j * 256) * 4;
            int r = i >> 8, c = i & 255;
            float4 v;
            if (c < 128) v = *(const float4*)&agg[(row0 + r) * D + c];
            else         v = *(const float4*)&x[(row0 + r) * D + (c - 128)];
            *(float4*)&rows[r][c] = v;
        }
        __syncthreads();
        float4 acc0 = make_float4(0, 0, 0, 0), acc1 = make_float4(0, 0, 0, 0);
#pragma unroll 8
        for (int k = 0; k < 256; ++k) {
            float4 wv = *(const float4*)&W2t[k][m4];
            float A0 = rows[rg][k], A1 = rows[rg + 8][k];
            acc0.x = fmaf(A0, wv.x, acc0.x); acc0.y = fmaf(A0, wv.y, acc0.y);
            acc0.z = fmaf(A0, wv.z, acc0.z); acc0.w = fmaf(A0, wv.w, acc0.w);
            acc1.x = fmaf(A1, wv.x, acc1.x); acc1.y = fmaf(A1, wv.y, acc1.y);
            acc1.z = fmaf(A1, wv.z, acc1.z); acc1.w = fmaf(A1, wv.w, acc1.w);
        }
        float4 b = *(const float4*)&brel[m4];
        *(float4*)&out[(row0 + rg) * D + m4] =
            make_float4(acc0.x + b.x, acc0.y + b.y, acc0.z + b.z, acc0.w + b.w);
        *(float4*)&out[(row0 + rg + 8) * D + m4] =
            make_float4(acc1.x + b.x, acc1.y + b.y, acc1.z + b.z, acc1.w + b.w);
    }
}

extern "C" void kernel_launch(void* const* d_in, const int* in_sizes, int n_in,
                              void* d_out, int out_size, void* d_ws, size_t ws_size,
                              hipStream_t stream) {
    const float* x     = (const float*)d_in[0];
    const int*   ei    = (const int*)d_in[1];
    const float* Wrel  = (const float*)d_in[2];
    const float* brel  = (const float*)d_in[3];
    const float* Wroot = (const float*)d_in[4];
    float* out = (float*)d_out;

    const size_t amatBytes = (size_t)N_NODES * K2 * sizeof(unsigned short); // 51.2 MB
    const size_t off2Bytes = (size_t)N_NODES * 2 * sizeof(int);             // 800 KB
    const size_t srcBytes  = (size_t)NBUCKET * CAPB * sizeof(int);          // 3.6 MB
    const size_t etmpBytes = (size_t)SB_BLOCKS * SB_EDGES * sizeof(unsigned);
    const size_t bboBytes  = (size_t)SB_BLOCKS * (NBUCKET + 1) * sizeof(int);
    const size_t wfBytes   = (size_t)4096 * 8 * sizeof(unsigned short);     // 64 KB
    auto align16 = [](size_t v) { return (v + 15) & ~(size_t)15; };

    size_t o_amat = 0;
    size_t o_off2 = align16(o_amat + amatBytes);
    size_t o_src  = align16(o_off2 + off2Bytes);
    size_t o_etmp = align16(o_src + srcBytes);
    size_t o_bbo  = align16(o_etmp + etmpBytes);
    size_t o_wf   = align16(o_bbo + bboBytes);
    size_t total  = o_wf + wfBytes;

    if (ws_size >= total) {
        char* ws = (char*)d_ws;
        unsigned short* Amat   = (unsigned short*)(ws + o_amat);
        int*      offs2        = (int*)(ws + o_off2);
        int*      srcSortedPad = (int*)(ws + o_src);
        unsigned* edgeTmp      = (unsigned*)(ws + o_etmp);
        int*      blockBucketOff = (int*)(ws + o_bbo);
        unsigned short* Wfrag  = (unsigned short*)(ws + o_wf);

        mega_kernel<<<CONV_BLOCKS + WPREP_BLOCKS + SB_BLOCKS, 256, 0, stream>>>(
            x, Amat, Wrel, Wroot, Wfrag, ei, edgeTmp, blockBucketOff);
        finalize_kernel<<<NBUCKET, 256, 0, stream>>>(edgeTmp, blockBucketOff,
                                                     offs2, srcSortedPad);
        seg_sum_kernel<<<(N_NODES / 4 * 64 + 255) / 256, 256, 0, stream>>>(
            offs2, srcSortedPad, Amat);
        gemm_mfma<<<(N_NODES + 255) / 256, 512, 0, stream>>>(Amat, Wfrag, brel, out);
    } else {
        // Fallback: atomic scatter + fp32 GEMM.
        float* agg = (ws_size >= (size_t)N_NODES * D * sizeof(float)) ? (float*)d_ws : out;
        hipMemsetAsync(agg, 0, (size_t)N_NODES * D * sizeof(float), stream);
        scatter_kernel<<<(N_EDGES * 32 + 255) / 256, 256, 0, stream>>>(x, ei, agg);
        fused_gemm<<<256, 256, 0, stream>>>(agg, x, Wrel, brel, Wroot, out,
                                            N_NODES / 16);
    }
}

// Round 12
// 89.310 us; speedup vs baseline: 1.7935x; 1.0033x over previous
//
#include <hip/hip_runtime.h>

#define N_NODES 100000
#define N_EDGES 600000
#define D 128
#define K2 256          // stacked K = [agg | x]

#define NBUCKET 196        // ceil(N_NODES / 512); bucket = dst >> 9
#define SB_EPT 8
#define SB_EDGES (256 * SB_EPT)                          // 2048 edges/block
#define SB_BLOCKS ((N_EDGES + SB_EDGES - 1) / SB_EDGES)  // 293
#define CAPB 4608          // padded per-bucket capacity (mean 3072, sigma~55)

#define CONV_BLOCKS 6250   // N_NODES*16 / 256 exactly
#define WPREP_BLOCKS 16    // 4096 slots / 256

typedef __attribute__((ext_vector_type(8))) short short8;
typedef __attribute__((ext_vector_type(4))) float f32x4;

__device__ __forceinline__ unsigned short f2bf(float f) {
    union { float f; unsigned u; } v; v.f = f;
    unsigned u = v.u;
    u += 0x7FFFu + ((u >> 16) & 1u);     // round-to-nearest-even
    return (unsigned short)(u >> 16);
}

__device__ __forceinline__ float bf_lo(unsigned u) {
    union { unsigned u; float f; } v; v.u = u << 16; return v.f;
}
__device__ __forceinline__ float bf_hi(unsigned u) {
    union { unsigned u; float f; } v; v.u = u & 0xFFFF0000u; return v.f;
}

// ---------------------------------------------------------------------------
// mega: fused {convert_x | wprep | local_sort}.  All three block families
// are mutually independent (local_sort needs NO global state: each block
// writes its own edgeTmp region + per-block bucket offset table).
// ---------------------------------------------------------------------------
__global__ __launch_bounds__(256) void mega_kernel(
        const float* __restrict__ x,
        unsigned short* __restrict__ Amat,
        const float* __restrict__ Wrel,
        const float* __restrict__ Wroot,
        unsigned short* __restrict__ Wfrag,
        const int* __restrict__ ei,
        unsigned* __restrict__ edgeTmp,
        int* __restrict__ blockBucketOff) {
    __shared__ int cnt[NBUCKET];
    __shared__ int pos[NBUCKET];
    __shared__ int sh[256];
    int b = blockIdx.x;
    int tid = threadIdx.x;
    if (b < CONV_BLOCKS) {
        // convert_x: x fp32 -> Amat[:,128:256) bf16
        int t = b * 256 + tid;                  // < 1.6M exactly
        int n = t >> 4, c8 = (t & 15) * 8;
        const float4* p = (const float4*)&x[(size_t)n * D + c8];
        float4 v0 = p[0], v1 = p[1];
        uint4 o;
        o.x = (unsigned)f2bf(v0.x) | ((unsigned)f2bf(v0.y) << 16);
        o.y = (unsigned)f2bf(v0.z) | ((unsigned)f2bf(v0.w) << 16);
        o.z = (unsigned)f2bf(v1.x) | ((unsigned)f2bf(v1.y) << 16);
        o.w = (unsigned)f2bf(v1.z) | ((unsigned)f2bf(v1.w) << 16);
        *(uint4*)&Amat[(size_t)n * K2 + 128 + c8] = o;
    } else if (b < CONV_BLOCKS + WPREP_BLOCKS) {
        // wprep: pack [Wrel;Wroot] into MFMA B-fragment order, bf16.
        int slot = (b - CONV_BLOCKS) * 256 + tid;   // < 4096 exactly
        int lane = slot & 63;
        int ks = (slot >> 6) & 7;
        int ct = slot >> 9;
        int m = ct * 16 + (lane & 15);
        int k = ks * 32 + (lane >> 4) * 8;
        const float* src = (k < 128) ? &Wrel[(size_t)m * 128 + k]
                                     : &Wroot[(size_t)m * 128 + (k - 128)];
        uint4 o;
        o.x = (unsigned)f2bf(src[0]) | ((unsigned)f2bf(src[1]) << 16);
        o.y = (unsigned)f2bf(src[2]) | ((unsigned)f2bf(src[3]) << 16);
        o.z = (unsigned)f2bf(src[4]) | ((unsigned)f2bf(src[5]) << 16);
        o.w = (unsigned)f2bf(src[6]) | ((unsigned)f2bf(src[7]) << 16);
        *(uint4*)&Wfrag[(size_t)slot * 8] = o;
    } else {
        // local_sort: bucket-group this block's 2048 edges into its OWN
        // edgeTmp region; write per-block bucket offsets (197 ints).
        int sb = b - CONV_BLOCKS - WPREP_BLOCKS;
        for (int i = tid; i < NBUCKET; i += 256) cnt[i] = 0;
        __syncthreads();
        int e0 = sb * SB_EDGES + tid;
        unsigned pack[SB_EPT];
        int bk[SB_EPT], rk[SB_EPT];
#pragma unroll
        for (int j = 0; j < SB_EPT; ++j) {
            int e = e0 + j * 256;
            if (e < N_EDGES) {
                int s = ei[e];
                int d = ei[N_EDGES + e];
                pack[j] = (unsigned)s | ((unsigned)(d & 511) << 17);
                bk[j] = d >> 9;
                rk[j] = atomicAdd(&cnt[bk[j]], 1);
            } else bk[j] = -1;
        }
        __syncthreads();
        int v = (tid < NBUCKET) ? cnt[tid] : 0;
        sh[tid] = v;
        __syncthreads();
        for (int off = 1; off < 256; off <<= 1) {
            int u = (tid >= off) ? sh[tid - off] : 0;
            __syncthreads();
            sh[tid] += u;
            __syncthreads();
        }
        int excl = sh[tid] - v;             // tid==196 -> total valid count
        if (tid < NBUCKET) pos[tid] = excl;
        if (tid <= NBUCKET) blockBucketOff[sb * (NBUCKET + 1) + tid] = excl;
        __syncthreads();
#pragma unroll
        for (int j = 0; j < SB_EPT; ++j)
            if (bk[j] >= 0)
                edgeTmp[sb * SB_EDGES + pos[bk[j]] + rk[j]] = pack[j];
    }
}

// ---------------------------------------------------------------------------
// finalize: one block per bucket k.  Gathers the 293 per-block runs of
// bucket k into LDS staging (POSITION-PARALLEL: each thread binary-searches
// the run table -> 12 independent global loads instead of 12 serial ones),
// counts/scans the 512 local dsts, writes per-node (beg,end) into offs2 and
// srcs into PADDED srcSortedPad[k*CAPB..].  No global scan anywhere.
// ---------------------------------------------------------------------------
__global__ __launch_bounds__(256) void finalize_kernel(
        const unsigned* __restrict__ edgeTmp,
        const int* __restrict__ blockBucketOff,
        int* __restrict__ offs2, int* __restrict__ srcSortedPad) {
    __shared__ unsigned eLDS[CAPB];      // 18 KB staging
    __shared__ int bs[512], bn[512], bp[513];
    __shared__ int cnt[512], cur[512];
    __shared__ int sh[256];
    int k = blockIdx.x, tid = threadIdx.x;

    // per-source-block run begin/count for this bucket
    for (int b = tid; b < 512; b += 256) { bn[b] = 0; bs[b] = 0; }
    cnt[tid] = 0; cnt[tid + 256] = 0;
    __syncthreads();
    for (int b = tid; b < SB_BLOCKS; b += 256) {
        int s = blockBucketOff[b * (NBUCKET + 1) + k];
        int e = blockBucketOff[b * (NBUCKET + 1) + k + 1];
        bs[b] = s;
        bn[b] = e - s;
    }
    __syncthreads();
    // exclusive scan of 512 run-counts (pair trick)
    int c0 = bn[2 * tid], c1 = bn[2 * tid + 1];
    int ps = c0 + c1;
    sh[tid] = ps;
    __syncthreads();
    for (int off = 1; off < 256; off <<= 1) {
        int u = (tid >= off) ? sh[tid - off] : 0;
        __syncthreads();
        sh[tid] += u;
        __syncthreads();
    }
    int pexcl = sh[tid] - ps;
    bp[2 * tid] = pexcl;
    bp[2 * tid + 1] = pexcl + c0;
    __syncthreads();
    int total = bp[511] + bn[511];
    if (total > CAPB) total = CAPB;      // statistically impossible; safety
    if (tid == 0) bp[512] = total;       // sentinel for binary search
    __syncthreads();
    // position-parallel copy of runs into staging
    for (int p = tid; p < total; p += 256) {
        int lo = 0, hi = 511;            // largest r with bp[r] <= p
        while (lo < hi) {
            int mid = (lo + hi + 1) >> 1;
            if (bp[mid] <= p) lo = mid; else hi = mid - 1;
        }
        eLDS[p] = edgeTmp[lo * SB_EDGES + bs[lo] + (p - bp[lo])];
    }
    __syncthreads();
    // count local dsts
    for (int i = tid; i < total; i += 256)
        atomicAdd(&cnt[eLDS[i] >> 17], 1);
    __syncthreads();
    // exclusive scan of 512 dst-counts (pair trick)
    c0 = cnt[2 * tid]; c1 = cnt[2 * tid + 1];
    ps = c0 + c1;
    sh[tid] = ps;
    __syncthreads();
    for (int off = 1; off < 256; off <<= 1) {
        int u = (tid >= off) ? sh[tid - off] : 0;
        __syncthreads();
        sh[tid] += u;
        __syncthreads();
    }
    int base = k * CAPB;
    pexcl = sh[tid] - ps + base;
    cur[2 * tid] = pexcl;
    cur[2 * tid + 1] = pexcl + c0;
    int d = (k << 9) + 2 * tid;
    if (d < N_NODES) {
        offs2[2 * d] = pexcl;
        offs2[2 * d + 1] = pexcl + c0;
    }
    if (d + 1 < N_NODES) {
        offs2[2 * d + 2] = pexcl + c0;
        offs2[2 * d + 3] = pexcl + c0 + c1;
    }
    __syncthreads();
    for (int i = tid; i < total; i += 256) {
        unsigned p = eLDS[i];
        int posn = atomicAdd(&cur[p >> 17], 1);
        srcSortedPad[posn] = (int)(p & 0x1FFFFu);
    }
}

// ---------------------------------------------------------------------------
// seg_sum v5: quarter-wave gather (16 lanes x 16B = one 256B bf16 row per
// instruction); 4 nodes/wave; FOUR edges in flight per quarter (4KB/wave,
// 2x v4's MLP); per-node (beg,end) from offs2 (padded layout).
// ---------------------------------------------------------------------------
__global__ void seg_sum_kernel(const int* __restrict__ offs2,
                               const int* __restrict__ srcSortedPad,
                               unsigned short* __restrict__ Amat) {
    int wave = (blockIdx.x * blockDim.x + threadIdx.x) >> 6;
    int lane = threadIdx.x & 63;
    int node = wave * 4 + (lane >> 4);
    if (node >= N_NODES) return;
    int c8 = (lane & 15) * 8;          // 8 bf16 cols = 16 B per lane
    int2 be = *(const int2*)&offs2[2 * node];
    int beg = be.x, end = be.y;
    float a0 = 0, a1 = 0, a2 = 0, a3 = 0, a4 = 0, a5 = 0, a6 = 0, a7 = 0;
    int p = beg;
    for (; p + 3 < end; p += 4) {      // 4 independent gathers in flight
        int s0 = srcSortedPad[p],     s1 = srcSortedPad[p + 1];
        int s2 = srcSortedPad[p + 2], s3 = srcSortedPad[p + 3];
        uint4 u0 = *(const uint4*)&Amat[(size_t)s0 * K2 + 128 + c8];
        uint4 u1 = *(const uint4*)&Amat[(size_t)s1 * K2 + 128 + c8];
        uint4 u2 = *(const uint4*)&Amat[(size_t)s2 * K2 + 128 + c8];
        uint4 u3 = *(const uint4*)&Amat[(size_t)s3 * K2 + 128 + c8];
        a0 += (bf_lo(u0.x) + bf_lo(u1.x)) + (bf_lo(u2.x) + bf_lo(u3.x));
        a1 += (bf_hi(u0.x) + bf_hi(u1.x)) + (bf_hi(u2.x) + bf_hi(u3.x));
        a2 += (bf_lo(u0.y) + bf_lo(u1.y)) + (bf_lo(u2.y) + bf_lo(u3.y));
        a3 += (bf_hi(u0.y) + bf_hi(u1.y)) + (bf_hi(u2.y) + bf_hi(u3.y));
        a4 += (bf_lo(u0.z) + bf_lo(u1.z)) + (bf_lo(u2.z) + bf_lo(u3.z));
        a5 += (bf_hi(u0.z) + bf_hi(u1.z)) + (bf_hi(u2.z) + bf_hi(u3.z));
        a6 += (bf_lo(u0.w) + bf_lo(u1.w)) + (bf_lo(u2.w) + bf_lo(u3.w));
        a7 += (bf_hi(u0.w) + bf_hi(u1.w)) + (bf_hi(u2.w) + bf_hi(u3.w));
    }
    for (; p + 1 < end; p += 2) {
        int s0 = srcSortedPad[p], s1 = srcSortedPad[p + 1];
        uint4 u0 = *(const uint4*)&Amat[(size_t)s0 * K2 + 128 + c8];
        uint4 u1 = *(const uint4*)&Amat[(size_t)s1 * K2 + 128 + c8];
        a0 += bf_lo(u0.x) + bf_lo(u1.x);
        a1 += bf_hi(u0.x) + bf_hi(u1.x);
        a2 += bf_lo(u0.y) + bf_lo(u1.y);
        a3 += bf_hi(u0.y) + bf_hi(u1.y);
        a4 += bf_lo(u0.z) + bf_lo(u1.z);
        a5 += bf_hi(u0.z) + bf_hi(u1.z);
        a6 += bf_lo(u0.w) + bf_lo(u1.w);
        a7 += bf_hi(u0.w) + bf_hi(u1.w);
    }
    if (p < end) {
        int s0 = srcSortedPad[p];
        uint4 u0 = *(const uint4*)&Amat[(size_t)s0 * K2 + 128 + c8];
        a0 += bf_lo(u0.x); a1 += bf_hi(u0.x);
        a2 += bf_lo(u0.y); a3 += bf_hi(u0.y);
        a4 += bf_lo(u0.z); a5 += bf_hi(u0.z);
        a6 += bf_lo(u0.w); a7 += bf_hi(u0.w);
    }
    uint4 o;
    o.x = (unsigned)f2bf(a0) | ((unsigned)f2bf(a1) << 16);
    o.y = (unsigned)f2bf(a2) | ((unsigned)f2bf(a3) << 16);
    o.z = (unsigned)f2bf(a4) | ((unsigned)f2bf(a5) << 16);
    o.w = (unsigned)f2bf(a6) | ((unsigned)f2bf(a7) << 16);
    *(uint4*)&Amat[(size_t)node * K2 + c8] = o;
}

// ---------------------------------------------------------------------------
// gemm_mfma v3: 512 threads / 8 waves / 256 rows per block (391 blocks).
// ---------------------------------------------------------------------------
__global__ __launch_bounds__(512, 4) void gemm_mfma(
        const unsigned short* __restrict__ Amat,
        const unsigned short* __restrict__ Wfrag,
        const float* __restrict__ brel,
        float* __restrict__ out) {
    __shared__ __align__(16) char smem[65536];
    short8* Wlds = (short8*)smem;
    float*  So   = (float*)smem;

    int tid = threadIdx.x;
    for (int i = tid; i < 4096; i += 512)
        Wlds[i] = *(const short8*)&Wfrag[(size_t)i * 8];
    __syncthreads();

    int lane = tid & 63;
    int w = tid >> 6;                    // 0..7
    int n16 = lane & 15, kg = lane >> 4;
    long rowB = (long)blockIdx.x * 256;
    long row0 = rowB + w * 32;

    long r0 = row0 + n16;
    long r1 = row0 + 16 + n16;
    long cr0 = (r0 < N_NODES) ? r0 : (N_NODES - 1);
    long cr1 = (r1 < N_NODES) ? r1 : (N_NODES - 1);
    const short8* a0p = (const short8*)(Amat + cr0 * K2 + kg * 8);
    const short8* a1p = (const short8*)(Amat + cr1 * K2 + kg * 8);

    f32x4 acc[2][8];
#pragma unroll
    for (int h = 0; h < 2; ++h)
#pragma unroll
        for (int ct = 0; ct < 8; ++ct)
            acc[h][ct] = (f32x4){0.f, 0.f, 0.f, 0.f};

    short8 a0v[4], a1v[4];
#pragma unroll
    for (int k = 0; k < 4; ++k) { a0v[k] = a0p[k * 4]; a1v[k] = a1p[k * 4]; }
#pragma unroll
    for (int ks = 0; ks < 4; ++ks) {
#pragma unroll
        for (int ct = 0; ct < 8; ++ct) {
            short8 b = Wlds[(ct * 8 + ks) * 64 + lane];
            acc[0][ct] = __builtin_amdgcn_mfma_f32_16x16x32_bf16(a0v[ks], b, acc[0][ct], 0, 0, 0);
            acc[1][ct] = __builtin_amdgcn_mfma_f32_16x16x32_bf16(a1v[ks], b, acc[1][ct], 0, 0, 0);
        }
    }
#pragma unroll
    for (int k = 0; k < 4; ++k) { a0v[k] = a0p[(k + 4) * 4]; a1v[k] = a1p[(k + 4) * 4]; }
#pragma unroll
    for (int ks = 4; ks < 8; ++ks) {
#pragma unroll
        for (int ct = 0; ct < 8; ++ct) {
            short8 b = Wlds[(ct * 8 + ks) * 64 + lane];
            acc[0][ct] = __builtin_amdgcn_mfma_f32_16x16x32_bf16(a0v[ks - 4], b, acc[0][ct], 0, 0, 0);
            acc[1][ct] = __builtin_amdgcn_mfma_f32_16x16x32_bf16(a1v[ks - 4], b, acc[1][ct], 0, 0, 0);
        }
    }

    __syncthreads();   // all waves done reading Wlds
    // D layout (m89): col = lane&15, row = 4*(lane>>4) + reg.
#pragma unroll
    for (int pass = 0; pass < 2; ++pass) {
        if ((w >> 2) == pass) {
            int wl = w & 3;
#pragma unroll
            for (int h = 0; h < 2; ++h)
#pragma unroll
                for (int ct = 0; ct < 8; ++ct) {
                    float bias = brel[ct * 16 + n16];
#pragma unroll
                    for (int r = 0; r < 4; ++r) {
                        int lrow = wl * 32 + h * 16 + kg * 4 + r;
                        int col = ct * 16 + n16;
                        So[lrow * 128 + (col ^ ((lrow & 7) << 2))] = acc[h][ct][r] + bias;
                    }
                }
        }
        __syncthreads();
#pragma unroll
        for (int j = 0; j < 8; ++j) {
            int g = tid + j * 512;
            int lrow = g >> 5;
            int q = g & 31;
            long grow = rowB + pass * 128 + lrow;
            if (grow < N_NODES) {
                float4 v = *(float4*)&So[lrow * 128 + ((q * 4) ^ ((lrow & 7) << 2))];
                *(float4*)&out[grow * 128 + q * 4] = v;
            }
        }
        __syncthreads();
    }
}

// ---------------------------------------------------------------------------
// Fallback (ws too small): atomic scatter + fp32 GEMM (round-1 path).
// ---------------------------------------------------------------------------
__global__ void scatter_kernel(const float* __restrict__ x,
                               const int* __restrict__ ei,
                               float* __restrict__ agg) {
    int gid = blockIdx.x * blockDim.x + threadIdx.x;
    int e = gid >> 5;
    if (e >= N_EDGES) return;
    int q = (gid & 31) * 4;
    int s = ei[e];
    int t = ei[N_EDGES + e];
    float4 v = *(const float4*)&x[(size_t)s * D + q];
    float* ap = &agg[(size_t)t * D + q];
    atomicAdd(ap + 0, v.x);
    atomicAdd(ap + 1, v.y);
    atomicAdd(ap + 2, v.z);
    atomicAdd(ap + 3, v.w);
}

__global__ __launch_bounds__(256, 1) void fused_gemm(
        const float* __restrict__ agg, const float* __restrict__ x,
        const float* __restrict__ Wrel, const float* __restrict__ brel,
        const float* __restrict__ Wroot, float* __restrict__ out,
        int nChunks) {
    __shared__ float W2t[256][128];
    __shared__ float rows[16][256];
    int tid = threadIdx.x;
    for (int idx = tid; idx < 256 * 128; idx += 256) {
        int k = idx >> 7, m = idx & 127;
        W2t[k][m] = (k < 128) ? Wrel[m * 128 + k] : Wroot[m * 128 + (k - 128)];
    }
    __syncthreads();
    int mq = tid & 31, rg = tid >> 5, m4 = mq * 4;
    for (int chunk = blockIdx.x; chunk < nChunks; chunk += gridDim.x) {
        size_t row0 = (size_t)chunk * 16;
        __syncthreads();
        for (int j = 0; j < 4; ++j) {
            int i = (tid + j * 256) * 4;
            int r = i >> 8, c = i & 255;
            float4 v;
            if (c < 128) v = *(const float4*)&agg[(row0 + r) * D + c];
            else         v = *(const float4*)&x[(row0 + r) * D + (c - 128)];
            *(float4*)&rows[r][c] = v;
        }
        __syncthreads();
        float4 acc0 = make_float4(0, 0, 0, 0), acc1 = make_float4(0, 0, 0, 0);
#pragma unroll 8
        for (int k = 0; k < 256; ++k) {
            float4 wv = *(const float4*)&W2t[k][m4];
            float A0 = rows[rg][k], A1 = rows[rg + 8][k];
            acc0.x = fmaf(A0, wv.x, acc0.x); acc0.y = fmaf(A0, wv.y, acc0.y);
            acc0.z = fmaf(A0, wv.z, acc0.z); acc0.w = fmaf(A0, wv.w, acc0.w);
            acc1.x = fmaf(A1, wv.x, acc1.x); acc1.y = fmaf(A1, wv.y, acc1.y);
            acc1.z = fmaf(A1, wv.z, acc1.z); acc1.w = fmaf(A1, wv.w, acc1.w);
        }
        float4 b = *(const float4*)&brel[m4];
        *(float4*)&out[(row0 + rg) * D + m4] =
            make_float4(acc0.x + b.x, acc0.y + b.y, acc0.z + b.z, acc0.w + b.w);
        *(float4*)&out[(row0 + rg + 8) * D + m4] =
            make_float4(acc1.x + b.x, acc1.y + b.y, acc1.z + b.z, acc1.w + b.w);
    }
}

extern "C" void kernel_launch(void* const* d_in, const int* in_sizes, int n_in,
                              void* d_out, int out_size, void* d_ws, size_t ws_size,
                              hipStream_t stream) {
    const float* x     = (const float*)d_in[0];
    const int*   ei    = (const int*)d_in[1];
    const float* Wrel  = (const float*)d_in[2];
    const float* brel  = (const float*)d_in[3];
    const float* Wroot = (const float*)d_in[4];
    float* out = (float*)d_out;

    const size_t amatBytes = (size_t)N_NODES * K2 * sizeof(unsigned short); // 51.2 MB
    const size_t off2Bytes = (size_t)N_NODES * 2 * sizeof(int);             // 800 KB
    const size_t srcBytes  = (size_t)NBUCKET * CAPB * sizeof(int);          // 3.6 MB
    const size_t etmpBytes = (size_t)SB_BLOCKS * SB_EDGES * sizeof(unsigned);
    const size_t bboBytes  = (size_t)SB_BLOCKS * (NBUCKET + 1) * sizeof(int);
    const size_t wfBytes   = (size_t)4096 * 8 * sizeof(unsigned short);     // 64 KB
    auto align16 = [](size_t v) { return (v + 15) & ~(size_t)15; };

    size_t o_amat = 0;
    size_t o_off2 = align16(o_amat + amatBytes);
    size_t o_src  = align16(o_off2 + off2Bytes);
    size_t o_etmp = align16(o_src + srcBytes);
    size_t o_bbo  = align16(o_etmp + etmpBytes);
    size_t o_wf   = align16(o_bbo + bboBytes);
    size_t total  = o_wf + wfBytes;

    if (ws_size >= total) {
        char* ws = (char*)d_ws;
        unsigned short* Amat   = (unsigned short*)(ws + o_amat);
        int*      offs2        = (int*)(ws + o_off2);
        int*      srcSortedPad = (int*)(ws + o_src);
        unsigned* edgeTmp      = (unsigned*)(ws + o_etmp);
        int*      blockBucketOff = (int*)(ws + o_bbo);
        unsigned short* Wfrag  = (unsigned short*)(ws + o_wf);

        mega_kernel<<<CONV_BLOCKS + WPREP_BLOCKS + SB_BLOCKS, 256, 0, stream>>>(
            x, Amat, Wrel, Wroot, Wfrag, ei, edgeTmp, blockBucketOff);
        finalize_kernel<<<NBUCKET, 256, 0, stream>>>(edgeTmp, blockBucketOff,
                                                     offs2, srcSortedPad);
        seg_sum_kernel<<<(N_NODES / 4 * 64 + 255) / 256, 256, 0, stream>>>(
            offs2, srcSortedPad, Amat);
        gemm_mfma<<<(N_NODES + 255) / 256, 512, 0, stream>>>(Amat, Wfrag, brel, out);
    } else {
        // Fallback: atomic scatter + fp32 GEMM.
        float* agg = (ws_size >= (size_t)N_NODES * D * sizeof(float)) ? (float*)d_ws : out;
        hipMemsetAsync(agg, 0, (size_t)N_NODES * D * sizeof(float), stream);
        scatter_kernel<<<(N_EDGES * 32 + 255) / 256, 256, 0, stream>>>(x, ei, agg);
        fused_gemm<<<256, 256, 0, stream>>>(agg, x, Wrel, brel, Wroot, out,
                                            N_NODES / 16);
    }
}